// Round 2
// baseline (9160.361 us; speedup 1.0000x reference)
//
#include <hip/hip_runtime.h>

#define B_N 256
#define F_N 256
#define NJ3 51
#define DH 512
#define G4 2048
#define CTX 563
#define OUT0 (B_N * F_N * NJ3)   // 3342336
#define CTXOFF OUT0
#define GRPN 32u                  // blocks per barrier group (one mt = 32 ng-slices)

typedef __attribute__((ext_vector_type(8))) short short8;
typedef __attribute__((ext_vector_type(4))) float floatx4;

__device__ __forceinline__ short f2bf(float f) {
  unsigned u = __float_as_uint(f);
  u = (u + 0x7fffu + ((u >> 16) & 1u)) >> 16;
  return (short)u;
}

// ---------------------------------------------------------------------------
// Generic fp32 tiled GEMM: C = act(A[M,K](lda) @ Bw[K,N] + bias)
// mode 0: relu -> out_f[M,N]
// mode 1: x_emb: write bf16 to out_h0 laid out [F][B][512]  (m = b*256+f)
// mode 2: z3 scatter: n<512 -> h0 bf16, <1024 -> h1 bf16, <1536 -> c0 f32, else c1
// mode 3: preds dual-write: out_f[m*51+n] and out_f2[m*563+512+n]
// ---------------------------------------------------------------------------
__global__ __launch_bounds__(256) void gemm_f32(
    const float* __restrict__ A, int lda,
    const float* __restrict__ Bw, const float* __restrict__ bias,
    int M, int N, int K, int mode,
    float* __restrict__ out_f, float* __restrict__ out_f2,
    short* __restrict__ out_h0, short* __restrict__ out_h1,
    float* __restrict__ out_c0, float* __restrict__ out_c1)
{
  __shared__ float As[16][64];
  __shared__ float Bs[16][68];
  int tid = threadIdx.x;
  int n0 = blockIdx.x * 64, m0 = blockIdx.y * 64;
  float acc[4][4] = {{0.f}};
  int ar = tid >> 2, ak = (tid & 3) * 4;
  int bk = tid >> 6, bn = tid & 63;
  int tm = (tid >> 4) * 4, tn = (tid & 15) * 4;
  for (int k0 = 0; k0 < K; k0 += 16) {
#pragma unroll
    for (int i = 0; i < 4; i++) {
      int kk = ak + i;
      float v = 0.f;
      if (k0 + kk < K) v = A[(long)(m0 + ar) * lda + k0 + kk];
      As[kk][ar] = v;
    }
#pragma unroll
    for (int i = 0; i < 4; i++) {
      int kk = bk + i * 4;
      float v = 0.f;
      if (k0 + kk < K && n0 + bn < N) v = Bw[(long)(k0 + kk) * N + n0 + bn];
      Bs[kk][bn] = v;
    }
    __syncthreads();
#pragma unroll
    for (int kk = 0; kk < 16; kk++) {
      float a0[4], b0[4];
#pragma unroll
      for (int i = 0; i < 4; i++) a0[i] = As[kk][tm + i];
#pragma unroll
      for (int j = 0; j < 4; j++) b0[j] = Bs[kk][tn + j];
#pragma unroll
      for (int i = 0; i < 4; i++)
#pragma unroll
        for (int j = 0; j < 4; j++) acc[i][j] += a0[i] * b0[j];
    }
    __syncthreads();
  }
#pragma unroll
  for (int i = 0; i < 4; i++) {
    int m = m0 + tm + i;
#pragma unroll
    for (int j = 0; j < 4; j++) {
      int n = n0 + tn + j;
      if (n >= N) continue;
      float v = acc[i][j] + bias[n];
      if (mode == 0) {
        out_f[(long)m * N + n] = fmaxf(v, 0.f);
      } else if (mode == 1) {
        int b = m >> 8, f = m & 255;
        out_h0[((long)f * 256 + b) * 512 + n] = f2bf(v);
      } else if (mode == 2) {
        int d = n & 511;
        if (n < 512)       out_h0[m * 512 + d] = f2bf(v);
        else if (n < 1024) out_h1[m * 512 + d] = f2bf(v);
        else if (n < 1536) out_c0[m * 512 + d] = v;
        else               out_c1[m * 512 + d] = v;
      } else {
        out_f[(long)m * NJ3 + n] = v;
        out_f2[(long)m * CTX + 512 + n] = v;
      }
    }
  }
}

// ---------------------------------------------------------------------------
// Pack weights (fp32 -> bf16) into exact MFMA B-fragment layout (see prior rev)
// ---------------------------------------------------------------------------
__global__ __launch_bounds__(256) void pack_b(
    short* __restrict__ dst, int KC, int mode,
    const float* __restrict__ Wih0, const float* __restrict__ Whh0,
    const float* __restrict__ Wih1, const float* __restrict__ Whh1,
    const float* __restrict__ dec_W)
{
  int idx = blockIdx.x * 256 + threadIdx.x;
  int total = KC * 32 * G4;
  if (idx >= total) return;
  int j = idx & 7;
  int l = (idx >> 3) & 63;
  int tt = idx >> 9;
  int kc = tt % KC;
  int nt = tt / KC;
  int k = kc * 32 + ((l >> 4) << 3) + j;
  int jp = nt * 16 + (l & 15);
  int jo = ((jp & 3) << 9) + (jp >> 2);
  float v = 0.f;
  if (mode == 0) {
    if (k < 512) v = Wih0[jo * 563 + k];
    else if (k < 1024) v = Whh0[jo * 512 + k - 512];
    else { int p = k - 1024; v = (p < NJ3) ? Wih0[jo * 563 + 512 + p] : 0.f; }
  } else if (mode == 1) {
    if (k < 512) v = Wih0[jo * 563 + k];
    else if (k < 1024) v = Whh0[jo * 512 + k - 512];
    else {
      int dd = k - 1024;
      float s = 0.f;
      for (int p = 0; p < NJ3; p++) s += dec_W[dd * NJ3 + p] * Wih0[jo * 563 + 512 + p];
      v = s;
    }
  } else {
    if (k < 512) v = Wih1[jo * 512 + k];
    else v = Whh1[jo * 512 + k - 512];
  }
  dst[idx] = f2bf(v);
}

// biases in j'=4d+g order; bias0B includes dec_b fold; pred0pad bf16 [256][64];
// also zeroes the 8*512 group-barrier counters used by the persistent scan.
__global__ __launch_bounds__(256) void prep_small(
    float* __restrict__ bias0A, float* __restrict__ bias0B, float* __restrict__ bias1,
    short* __restrict__ pred0pad, unsigned* __restrict__ bar,
    const float* __restrict__ bih0, const float* __restrict__ bhh0,
    const float* __restrict__ bih1, const float* __restrict__ bhh1,
    const float* __restrict__ Wih0, const float* __restrict__ dec_b,
    const float* __restrict__ init_p)
{
  int i = blockIdx.x * 256 + threadIdx.x;
  if (i < G4) {
    int jo = ((i & 3) << 9) + (i >> 2);
    float b0 = bih0[jo] + bhh0[jo];
    bias0A[i] = b0;
    float s = 0.f;
    for (int p = 0; p < NJ3; p++) s += dec_b[p] * Wih0[jo * 563 + 512 + p];
    bias0B[i] = b0 + s;
    bias1[i] = bih1[jo] + bhh1[jo];
  }
  if (i < 4096) bar[i] = 0u;
  if (i < 16384) {
    int b = i >> 6, p = i & 63;
    pred0pad[i] = (p < NJ3) ? f2bf(init_p[b * 85 + p]) : (short)0;
  }
}

// ---------------------------------------------------------------------------
// Split GROUP barrier (arrive/wait) over the 32 blocks of one mt-group; one
// counter per (group, phase). Release-RMW on arrive writes back the XCD L2 to
// the coherence point; acquire fence on wait-exit invalidates. sched_barrier
// pins the compiler from hoisting dependent loads across the wait.
// ---------------------------------------------------------------------------
__device__ __forceinline__ void bar_arrive(unsigned* c) {
  __builtin_amdgcn_sched_barrier(0);
  __syncthreads();  // all block stores drained (vmcnt 0) before publish
  if (threadIdx.x == 0)
    __hip_atomic_fetch_add(c, 1u, __ATOMIC_RELEASE, __HIP_MEMORY_SCOPE_AGENT);
}
__device__ __forceinline__ void bar_wait(unsigned* c) {
  if (threadIdx.x == 0) {
    while (__hip_atomic_load(c, __ATOMIC_RELAXED, __HIP_MEMORY_SCOPE_AGENT) < GRPN)
      __builtin_amdgcn_s_sleep(1);
    __builtin_amdgcn_fence(__ATOMIC_ACQUIRE, "agent");
  }
  __syncthreads();
  __builtin_amdgcn_sched_barrier(0);
}

// One K-segment of the per-wave dual 16x16x32 MFMA chain.
template<int NKC>
__device__ __forceinline__ void gseg(floatx4& acc0, floatx4& acc1,
    const short* A, int lda, int grow, int kgrp,
    const short8* bp0, const short8* bp1, int kcBase)
{
#pragma unroll
  for (int kc = 0; kc < NKC; kc++) {
    short8 a = *(const short8*)(A + (long)grow * lda + kc * 32 + kgrp * 8);
    short8 b0 = bp0[(kcBase + kc) * 64];
    short8 b1 = bp1[(kcBase + kc) * 64];
    acc0 = __builtin_amdgcn_mfma_f32_16x16x32_bf16(a, b0, acc0, 0, 0, 0);
    acc1 = __builtin_amdgcn_mfma_f32_16x16x32_bf16(a, b1, acc1, 0, 0, 0);
  }
}

struct ScanArgs {
  const short* B0A; const short* B0B; const short* B1;
  const float* bias0A; const float* bias0B; const float* bias1;
  const short* xemb; const short* pred0pad;
  short* h0a; short* h0b; short* h1a; short* h1b;
  const float* c0buf; const float* c1buf;
  float* ctx; unsigned* bar;
};

// ---------------------------------------------------------------------------
// Persistent scan: plain launch, 256 blocks = 1 block/CU (always co-resident;
// no cooperative launch -> graph-capture safe). Same (mt, ng) tiling + XCD
// swizzle as before. All inter-block h0/h1 exchange is WITHIN an mt-group of
// 32 blocks, so barriers are 32-arrival group barriers (8 decoupled groups).
// Per step: phase A (LSTM0) then phase B (LSTM1); dependency-free K-segments
// run BEFORE each wait so MFMA work hides barrier latency. c-state and biases
// live in registers for all 256 steps.
// ---------------------------------------------------------------------------
__global__ __launch_bounds__(256) void scan_kernel(ScanArgs A)
{
  __shared__ float gsm[32][68];
  const int tid = threadIdx.x;
  const int bid = blockIdx.x;
  const int ng = (bid & 7) + (((bid >> 3) & 3) << 3);
  const int mt = bid >> 5;
  const int m0 = mt * 32, n0 = ng * 64;
  const int lane = tid & 63, wid = tid >> 6;
  const int m_off = (wid & 1) * 16;
  const int wn = wid >> 1;
  const int grow = m0 + m_off + (lane & 15);
  const int kgrp = lane >> 4;
  const int crow = m_off + kgrp * 4;
  const int ccol = wn * 32 + (lane & 15);
  const int dl = tid & 15;
  const int blq = tid >> 4;           // 0..15
  const int d = ng * 16 + dl;
  unsigned* gbar = A.bar + mt * 512;  // this group's 512 phase counters

  const short8* b0A_0 = (const short8*)A.B0A + (long)(ng * 4 + wn * 2) * (34 * 64) + lane;
  const short8* b0A_1 = b0A_0 + 34 * 64;
  const short8* b0B_0 = (const short8*)A.B0B + (long)(ng * 4 + wn * 2) * (48 * 64) + lane;
  const short8* b0B_1 = b0B_0 + 48 * 64;
  const short8* b1_0  = (const short8*)A.B1  + (long)(ng * 4 + wn * 2) * (32 * 64) + lane;
  const short8* b1_1  = b1_0 + 32 * 64;

  // hoist biases and c-state into registers for the whole scan
  float bias0r[4], bias1r[4];
#pragma unroll
  for (int g = 0; g < 4; g++) {
    bias0r[g] = A.bias0B[n0 + dl * 4 + g];
    bias1r[g] = A.bias1[n0 + dl * 4 + g];
  }
  float c0r[2], c1r[2];
#pragma unroll
  for (int r = 0; r < 2; r++) {
    int b = m0 + blq + r * 16;
    c0r[r] = A.c0buf[b * 512 + d];
    c1r[r] = A.c1buf[b * 512 + d];
  }

  for (int t = 0; t < 256; t++) {
    const int p = t & 1;
    const short* h0p = p ? A.h0b : A.h0a;
    short* h0n       = p ? A.h0a : A.h0b;
    const short* h1p = p ? A.h1b : A.h1a;
    short* h1n       = p ? A.h1a : A.h1b;
    const short* xt = A.xemb + (long)t * (256 * 512);

    // ---- phase A: LSTM0 gates = [x | h0 | h1-fold] @ B0 ----
    floatx4 acc0 = {0.f, 0.f, 0.f, 0.f}, acc1 = {0.f, 0.f, 0.f, 0.f};
    float bA[4];
    if (t == 0) {
      gseg<16>(acc0, acc1, xt, 512, grow, kgrp, b0A_0, b0A_1, 0);
      gseg<16>(acc0, acc1, h0p, 512, grow, kgrp, b0A_0, b0A_1, 16);
      gseg<2>(acc0, acc1, A.pred0pad, 64, grow, kgrp, b0A_0, b0A_1, 32);
#pragma unroll
      for (int g = 0; g < 4; g++) bA[g] = A.bias0A[n0 + dl * 4 + g];
    } else {
      gseg<16>(acc0, acc1, xt, 512, grow, kgrp, b0B_0, b0B_1, 0);   // indep
      gseg<16>(acc0, acc1, h0p, 512, grow, kgrp, b0B_0, b0B_1, 16); // indep
      bar_wait(gbar + 2 * t - 1);                                   // b_{t-1}
      gseg<16>(acc0, acc1, h1p, 512, grow, kgrp, b0B_0, b0B_1, 32); // fold (dep)
#pragma unroll
      for (int g = 0; g < 4; g++) bA[g] = bias0r[g];
    }
#pragma unroll
    for (int r = 0; r < 4; r++) {
      gsm[crow + r][ccol] = acc0[r];
      gsm[crow + r][ccol + 16] = acc1[r];
    }
    __syncthreads();
#pragma unroll
    for (int r = 0; r < 2; r++) {
      int bl = blq + r * 16;
      int b = m0 + bl;
      float gi = gsm[bl][dl * 4 + 0] + bA[0];
      float gf = gsm[bl][dl * 4 + 1] + bA[1];
      float gg = gsm[bl][dl * 4 + 2] + bA[2];
      float go = gsm[bl][dl * 4 + 3] + bA[3];
      float is = 1.f / (1.f + __expf(-gi));
      float fs = 1.f / (1.f + __expf(-gf));
      float os = 1.f / (1.f + __expf(-go));
      float gt = tanhf(gg);
      float cn = fs * c0r[r] + is * gt;
      c0r[r] = cn;
      float hn = os * tanhf(cn);
      h0n[b * 512 + d] = f2bf(hn);
    }
    bar_arrive(gbar + 2 * t);                                       // a_t

    // ---- phase B: LSTM1 gates = [h0_new | h1_prev] @ B1 ----
    floatx4 p0 = {0.f, 0.f, 0.f, 0.f}, p1 = {0.f, 0.f, 0.f, 0.f};
    gseg<16>(p0, p1, h1p, 512, grow, kgrp, b1_0, b1_1, 16);         // indep (Whh1)
    bar_wait(gbar + 2 * t);                                         // a_t
    gseg<16>(p0, p1, h0n, 512, grow, kgrp, b1_0, b1_1, 0);          // dep (Wih1)
#pragma unroll
    for (int r = 0; r < 4; r++) {
      gsm[crow + r][ccol] = p0[r];
      gsm[crow + r][ccol + 16] = p1[r];
    }
    __syncthreads();
    float* ctx_t = A.ctx + (long)t * CTX;
#pragma unroll
    for (int r = 0; r < 2; r++) {
      int bl = blq + r * 16;
      int b = m0 + bl;
      float gi = gsm[bl][dl * 4 + 0] + bias1r[0];
      float gf = gsm[bl][dl * 4 + 1] + bias1r[1];
      float gg = gsm[bl][dl * 4 + 2] + bias1r[2];
      float go = gsm[bl][dl * 4 + 3] + bias1r[3];
      float is = 1.f / (1.f + __expf(-gi));
      float fs = 1.f / (1.f + __expf(-gf));
      float os = 1.f / (1.f + __expf(-go));
      float gt = tanhf(gg);
      float cn = fs * c1r[r] + is * gt;
      c1r[r] = cn;
      float hn = os * tanhf(cn);
      h1n[b * 512 + d] = f2bf(hn);
      ctx_t[(long)b * (256L * CTX) + d] = hn;
    }
    if (t < 255) bar_arrive(gbar + 2 * t + 1);                      // b_t
  }
}

extern "C" void kernel_launch(void* const* d_in, const int* in_sizes, int n_in,
                              void* d_out, int out_size, void* d_ws, size_t ws_size,
                              hipStream_t stream)
{
  const float* x       = (const float*)d_in[0];
  const float* init_p  = (const float*)d_in[1];
  const float* embed_W = (const float*)d_in[2];
  const float* embed_b = (const float*)d_in[3];
  const float* ni_W1   = (const float*)d_in[4];
  const float* ni_b1   = (const float*)d_in[5];
  const float* ni_W2   = (const float*)d_in[6];
  const float* ni_b2   = (const float*)d_in[7];
  const float* ni_W3   = (const float*)d_in[8];
  const float* ni_b3   = (const float*)d_in[9];
  const float* Wih0    = (const float*)d_in[10];
  const float* Whh0    = (const float*)d_in[11];
  const float* bih0    = (const float*)d_in[12];
  const float* bhh0    = (const float*)d_in[13];
  const float* Wih1    = (const float*)d_in[14];
  const float* Whh1    = (const float*)d_in[15];
  const float* bih1    = (const float*)d_in[16];
  const float* bhh1    = (const float*)d_in[17];
  const float* dec_W   = (const float*)d_in[18];
  const float* dec_b   = (const float*)d_in[19];
  float* out = (float*)d_out;
  char* ws = (char*)d_ws;

  // workspace layout (all 256B-aligned)
  short* xemb = (short*)(ws + 0);                 // [F][B][512] bf16, 67108864 B
  short* B0A  = (short*)(ws + 67108864);          // 1088*2048*2
  short* B0B  = (short*)(ws + 71565312);          // 1536*2048*2
  short* B1p  = (short*)(ws + 77856768);          // 1024*2048*2
  short* Sh0[2] = { (short*)(ws + 82051072), (short*)(ws + 82575360) };
  short* Sh1[2] = { (short*)(ws + 82313216), (short*)(ws + 82837504) };
  float* c0     = (float*)(ws + 83099648);
  float* c1     = (float*)(ws + 83623936);
  float* bias0A = (float*)(ws + 84148224);
  float* bias0B = (float*)(ws + 84156416);
  float* bias1  = (float*)(ws + 84164608);
  short* pred0pad = (short*)(ws + 84172800);      // [256][64] bf16
  float* z1 = (float*)(ws + 84205568);
  float* z2 = (float*)(ws + 84729856);
  unsigned* bar = (unsigned*)(ws + 85778432);     // 8 groups x 512 counters
  (void)in_sizes; (void)n_in; (void)out_size; (void)ws_size;

  // ---- one-time prep (re-run every call; ws is re-poisoned by harness) ----
  pack_b<<<8704, 256, 0, stream>>>(B0A, 34, 0, Wih0, Whh0, Wih1, Whh1, dec_W);
  pack_b<<<12288, 256, 0, stream>>>(B0B, 48, 1, Wih0, Whh0, Wih1, Whh1, dec_W);
  pack_b<<<8192, 256, 0, stream>>>(B1p, 32, 2, Wih0, Whh0, Wih1, Whh1, dec_W);
  prep_small<<<64, 256, 0, stream>>>(bias0A, bias0B, bias1, pred0pad, bar,
                                     bih0, bhh0, bih1, bhh1, Wih0, dec_b, init_p);
  // x_emb = x @ embed_W + embed_b  -> bf16 [F][B][512]
  gemm_f32<<<dim3(8, 1024), 256, 0, stream>>>(x, 34, embed_W, embed_b,
      65536, 512, 34, 1, nullptr, nullptr, xemb, nullptr, nullptr, nullptr);
  // init MLP: z1 = relu(init@W1+b1); z2 = relu(z1@W2+b2); z3 = z2@W3+b3 -> h/c scatter
  gemm_f32<<<dim3(8, 4), 256, 0, stream>>>(init_p, 85, ni_W1, ni_b1,
      256, 512, 85, 0, z1, nullptr, nullptr, nullptr, nullptr, nullptr);
  gemm_f32<<<dim3(16, 4), 256, 0, stream>>>(z1, 512, ni_W2, ni_b2,
      256, 1024, 512, 0, z2, nullptr, nullptr, nullptr, nullptr, nullptr);
  gemm_f32<<<dim3(32, 4), 256, 0, stream>>>(z2, 1024, ni_W3, ni_b3,
      256, 2048, 1024, 2, nullptr, nullptr, Sh0[0], Sh1[0], c0, c1);

  // ---- persistent scan: ONE plain kernel, 256 blocks (1/CU, co-resident) ----
  ScanArgs sa;
  sa.B0A = B0A; sa.B0B = B0B; sa.B1 = B1p;
  sa.bias0A = bias0A; sa.bias0B = bias0B; sa.bias1 = bias1;
  sa.xemb = xemb; sa.pred0pad = pred0pad;
  sa.h0a = Sh0[0]; sa.h0b = Sh0[1]; sa.h1a = Sh1[0]; sa.h1b = Sh1[1];
  sa.c0buf = c0; sa.c1buf = c1;
  sa.ctx = out + CTXOFF; sa.bar = bar;
  scan_kernel<<<256, 256, 0, stream>>>(sa);

  // ---- preds = ctx @ dec_W + dec_b -> pred_kp3d + motion_context[...,512:] ----
  gemm_f32<<<dim3(1, 1024), 256, 0, stream>>>(out + CTXOFF, CTX, dec_W, dec_b,
      65536, NJ3, 512, 3, out, out + CTXOFF, nullptr, nullptr, nullptr, nullptr);
}

// Round 3
// 4930.283 us; speedup vs baseline: 1.8580x; 1.8580x over previous
//
#include <hip/hip_runtime.h>

#define B_N 256
#define F_N 256
#define NJ3 51
#define DH 512
#define G4 2048
#define CTX 563
#define OUT0 (B_N * F_N * NJ3)   // 3342336
#define CTXOFF OUT0
#define GRPN 32u                  // blocks per barrier group (one mt = 32 ng-slices)

typedef __attribute__((ext_vector_type(8))) short short8;
typedef __attribute__((ext_vector_type(4))) float floatx4;

__device__ __forceinline__ short f2bf(float f) {
  unsigned u = __float_as_uint(f);
  u = (u + 0x7fffu + ((u >> 16) & 1u)) >> 16;
  return (short)u;
}

// ---------------------------------------------------------------------------
// Generic fp32 tiled GEMM (unchanged): C = act(A[M,K](lda) @ Bw[K,N] + bias)
// ---------------------------------------------------------------------------
__global__ __launch_bounds__(256) void gemm_f32(
    const float* __restrict__ A, int lda,
    const float* __restrict__ Bw, const float* __restrict__ bias,
    int M, int N, int K, int mode,
    float* __restrict__ out_f, float* __restrict__ out_f2,
    short* __restrict__ out_h0, short* __restrict__ out_h1,
    float* __restrict__ out_c0, float* __restrict__ out_c1)
{
  __shared__ float As[16][64];
  __shared__ float Bs[16][68];
  int tid = threadIdx.x;
  int n0 = blockIdx.x * 64, m0 = blockIdx.y * 64;
  float acc[4][4] = {{0.f}};
  int ar = tid >> 2, ak = (tid & 3) * 4;
  int bk = tid >> 6, bn = tid & 63;
  int tm = (tid >> 4) * 4, tn = (tid & 15) * 4;
  for (int k0 = 0; k0 < K; k0 += 16) {
#pragma unroll
    for (int i = 0; i < 4; i++) {
      int kk = ak + i;
      float v = 0.f;
      if (k0 + kk < K) v = A[(long)(m0 + ar) * lda + k0 + kk];
      As[kk][ar] = v;
    }
#pragma unroll
    for (int i = 0; i < 4; i++) {
      int kk = bk + i * 4;
      float v = 0.f;
      if (k0 + kk < K && n0 + bn < N) v = Bw[(long)(k0 + kk) * N + n0 + bn];
      Bs[kk][bn] = v;
    }
    __syncthreads();
#pragma unroll
    for (int kk = 0; kk < 16; kk++) {
      float a0[4], b0[4];
#pragma unroll
      for (int i = 0; i < 4; i++) a0[i] = As[kk][tm + i];
#pragma unroll
      for (int j = 0; j < 4; j++) b0[j] = Bs[kk][tn + j];
#pragma unroll
      for (int i = 0; i < 4; i++)
#pragma unroll
        for (int j = 0; j < 4; j++) acc[i][j] += a0[i] * b0[j];
    }
    __syncthreads();
  }
#pragma unroll
  for (int i = 0; i < 4; i++) {
    int m = m0 + tm + i;
#pragma unroll
    for (int j = 0; j < 4; j++) {
      int n = n0 + tn + j;
      if (n >= N) continue;
      float v = acc[i][j] + bias[n];
      if (mode == 0) {
        out_f[(long)m * N + n] = fmaxf(v, 0.f);
      } else if (mode == 1) {
        int b = m >> 8, f = m & 255;
        out_h0[((long)f * 256 + b) * 512 + n] = f2bf(v);
      } else if (mode == 2) {
        int d = n & 511;
        if (n < 512)       out_h0[m * 512 + d] = f2bf(v);
        else if (n < 1024) out_h1[m * 512 + d] = f2bf(v);
        else if (n < 1536) out_c0[m * 512 + d] = v;
        else               out_c1[m * 512 + d] = v;
      } else {
        out_f[(long)m * NJ3 + n] = v;
        out_f2[(long)m * CTX + 512 + n] = v;
      }
    }
  }
}

// ---------------------------------------------------------------------------
// Pack weights (fp32 -> bf16) into exact MFMA B-fragment layout (unchanged)
// ---------------------------------------------------------------------------
__global__ __launch_bounds__(256) void pack_b(
    short* __restrict__ dst, int KC, int mode,
    const float* __restrict__ Wih0, const float* __restrict__ Whh0,
    const float* __restrict__ Wih1, const float* __restrict__ Whh1,
    const float* __restrict__ dec_W)
{
  int idx = blockIdx.x * 256 + threadIdx.x;
  int total = KC * 32 * G4;
  if (idx >= total) return;
  int j = idx & 7;
  int l = (idx >> 3) & 63;
  int tt = idx >> 9;
  int kc = tt % KC;
  int nt = tt / KC;
  int k = kc * 32 + ((l >> 4) << 3) + j;
  int jp = nt * 16 + (l & 15);
  int jo = ((jp & 3) << 9) + (jp >> 2);
  float v = 0.f;
  if (mode == 0) {
    if (k < 512) v = Wih0[jo * 563 + k];
    else if (k < 1024) v = Whh0[jo * 512 + k - 512];
    else { int p = k - 1024; v = (p < NJ3) ? Wih0[jo * 563 + 512 + p] : 0.f; }
  } else if (mode == 1) {
    if (k < 512) v = Wih0[jo * 563 + k];
    else if (k < 1024) v = Whh0[jo * 512 + k - 512];
    else {
      int dd = k - 1024;
      float s = 0.f;
      for (int p = 0; p < NJ3; p++) s += dec_W[dd * NJ3 + p] * Wih0[jo * 563 + 512 + p];
      v = s;
    }
  } else {
    if (k < 512) v = Wih1[jo * 512 + k];
    else v = Whh1[jo * 512 + k - 512];
  }
  dst[idx] = f2bf(v);
}

// biases in j'=4d+g order; bias0B includes dec_b fold; pred0pad bf16 [256][64];
// zeroes the 8*512 group-barrier counters.
__global__ __launch_bounds__(256) void prep_small(
    float* __restrict__ bias0A, float* __restrict__ bias0B, float* __restrict__ bias1,
    short* __restrict__ pred0pad, unsigned* __restrict__ bar,
    const float* __restrict__ bih0, const float* __restrict__ bhh0,
    const float* __restrict__ bih1, const float* __restrict__ bhh1,
    const float* __restrict__ Wih0, const float* __restrict__ dec_b,
    const float* __restrict__ init_p)
{
  int i = blockIdx.x * 256 + threadIdx.x;
  if (i < G4) {
    int jo = ((i & 3) << 9) + (i >> 2);
    float b0 = bih0[jo] + bhh0[jo];
    bias0A[i] = b0;
    float s = 0.f;
    for (int p = 0; p < NJ3; p++) s += dec_b[p] * Wih0[jo * 563 + 512 + p];
    bias0B[i] = b0 + s;
    bias1[i] = bih1[jo] + bhh1[jo];
  }
  if (i < 4096) bar[i] = 0u;
  if (i < 16384) {
    int b = i >> 6, p = i & 63;
    pred0pad[i] = (p < NJ3) ? f2bf(init_p[b * 85 + p]) : (short)0;
  }
}

// ---------------------------------------------------------------------------
// Targeted coherence primitives. NO cache-wide fences anywhere:
//  - h-data stores/loads use sc0 sc1 (bypass L1+L2, coherence point = MALL)
//  - barrier counters use RELAXED agent atomics (no buffer_wbl2/buffer_inv)
//  - ordering: vmcnt(0) drain before arrive; control-dep + sched_barrier after
//    wait. Weights/xemb stay normally cached -> L2-resident for whole scan.
// ---------------------------------------------------------------------------
__device__ __forceinline__ void ld16_coh(short8* dst, const void* p) {
  asm volatile("global_load_dwordx4 %0, %1, off sc0 sc1"
               : "=v"(*dst) : "v"(p) : "memory");
}
__device__ __forceinline__ void st2_coh(void* p, unsigned v) {
  asm volatile("global_store_short %0, %1, off sc0 sc1"
               :: "v"(p), "v"(v) : "memory");
}
__device__ __forceinline__ void vmem_drain() {
  asm volatile("s_waitcnt vmcnt(0)" ::: "memory");
  __builtin_amdgcn_sched_barrier(0);
}

__device__ __forceinline__ void bar_arrive(unsigned* c) {
  vmem_drain();        // all coherent stores ack'd at MALL before publish
  __syncthreads();     // every wave of the block has drained
  if (threadIdx.x == 0)
    __hip_atomic_fetch_add(c, 1u, __ATOMIC_RELAXED, __HIP_MEMORY_SCOPE_AGENT);
}
__device__ __forceinline__ void bar_wait(unsigned* c) {
  if (threadIdx.x == 0) {
    while (__hip_atomic_load(c, __ATOMIC_RELAXED, __HIP_MEMORY_SCOPE_AGENT) < GRPN)
      __builtin_amdgcn_s_sleep(1);
  }
  __syncthreads();
  __builtin_amdgcn_sched_barrier(0);
}

// Global-cached A-operand segment (x / pred paths).
template<int NKC>
__device__ __forceinline__ void gseg(floatx4& acc0, floatx4& acc1,
    const short* A, int lda, int grow, int kgrp,
    const short8* bp0, const short8* bp1, int kcBase)
{
#pragma unroll
  for (int kc = 0; kc < NKC; kc++) {
    short8 a = *(const short8*)(A + (long)grow * lda + kc * 32 + kgrp * 8);
    short8 b0 = bp0[(kcBase + kc) * 64];
    short8 b1 = bp1[(kcBase + kc) * 64];
    acc0 = __builtin_amdgcn_mfma_f32_16x16x32_bf16(a, b0, acc0, 0, 0, 0);
    acc1 = __builtin_amdgcn_mfma_f32_16x16x32_bf16(a, b1, acc1, 0, 0, 0);
  }
}

// LDS-panel A-operand segment. Panel is [32 rows][1024 B] with byte-col XOR
// swizzle ((row&7)<<4) -> ds_read_b128 is ~2-way (free, m136).
template<int NKC>
__device__ __forceinline__ void gsegL(floatx4& acc0, floatx4& acc1,
    const char* panel, int lrowb, int swz, int kgrp,
    const short8* bp0, const short8* bp1, int kcBase)
{
#pragma unroll
  for (int kc = 0; kc < NKC; kc++) {
    short8 a = *(const short8*)(panel + lrowb + ((kc * 64 + kgrp * 16) ^ swz));
    short8 b0 = bp0[(kcBase + kc) * 64];
    short8 b1 = bp1[(kcBase + kc) * 64];
    acc0 = __builtin_amdgcn_mfma_f32_16x16x32_bf16(a, b0, acc0, 0, 0, 0);
    acc1 = __builtin_amdgcn_mfma_f32_16x16x32_bf16(a, b1, acc1, 0, 0, 0);
  }
}

// Coherent panel staging: issue 8x16B loads/thread (32 KB panel).
__device__ __forceinline__ void stage_issue(short8 r[8], const short* src,
                                            int m0, int tid) {
#pragma unroll
  for (int i = 0; i < 8; i++) {
    int e16 = i * 256 + tid;
    int row = e16 >> 6;             // 64 x 16B chunks per 1024B row
    int colb = (e16 & 63) * 16;
    ld16_coh(&r[i], (const char*)src + (long)(m0 + row) * 1024 + colb);
  }
}
__device__ __forceinline__ void stage_write(char* panel, short8 r[8], int tid) {
#pragma unroll
  for (int i = 0; i < 8; i++) {
    int e16 = i * 256 + tid;
    int row = e16 >> 6;
    int colb = (e16 & 63) * 16;
    *(short8*)(panel + row * 1024 + (colb ^ ((row & 7) << 4))) = r[i];
  }
}

struct ScanArgs {
  const short* B0A; const short* B0B; const short* B1;
  const float* bias0A; const float* bias0B; const float* bias1;
  const short* xemb; const short* pred0pad;
  short* h0a; short* h0b; short* h1a; short* h1b;
  const float* c0buf; const float* c1buf;
  float* ctx; unsigned* bar;
};

// ---------------------------------------------------------------------------
// Persistent scan: 256 blocks = 1/CU (co-resident by construction). Weights
// cached in per-XCD L2 for all 256 steps (never invalidated). h exchange via
// MALL-coherent accesses only; group barriers (32 arrivals) relaxed atomics.
// ---------------------------------------------------------------------------
__global__ __launch_bounds__(256) void scan_kernel(ScanArgs A)
{
  __shared__ float gsm[32][68];
  __shared__ char lds0[32 * 1024];   // h0p / h0n panel
  __shared__ char lds1[32 * 1024];   // h1p panel
  const int tid = threadIdx.x;
  const int bid = blockIdx.x;
  const int ng = (bid & 7) + (((bid >> 3) & 3) << 3);
  const int mt = bid >> 5;
  const int m0 = mt * 32, n0 = ng * 64;
  const int lane = tid & 63, wid = tid >> 6;
  const int m_off = (wid & 1) * 16;
  const int wn = wid >> 1;
  const int grow = m0 + m_off + (lane & 15);
  const int kgrp = lane >> 4;
  const int lr = m_off + (lane & 15);
  const int lrowb = lr * 1024;
  const int swz = (lr & 7) << 4;
  const int crow = m_off + kgrp * 4;
  const int ccol = wn * 32 + (lane & 15);
  const int dl = tid & 15;
  const int blq = tid >> 4;           // 0..15
  const int d = ng * 16 + dl;
  unsigned* gbar = A.bar + mt * 512;

  const short8* b0A_0 = (const short8*)A.B0A + (long)(ng * 4 + wn * 2) * (34 * 64) + lane;
  const short8* b0A_1 = b0A_0 + 34 * 64;
  const short8* b0B_0 = (const short8*)A.B0B + (long)(ng * 4 + wn * 2) * (48 * 64) + lane;
  const short8* b0B_1 = b0B_0 + 48 * 64;
  const short8* b1_0  = (const short8*)A.B1  + (long)(ng * 4 + wn * 2) * (32 * 64) + lane;
  const short8* b1_1  = b1_0 + 32 * 64;

  // biases and c-state live in registers for the whole scan
  float bias0r[4], bias1r[4];
#pragma unroll
  for (int g = 0; g < 4; g++) {
    bias0r[g] = A.bias0B[n0 + dl * 4 + g];
    bias1r[g] = A.bias1[n0 + dl * 4 + g];
  }
  float c0r[2], c1r[2];
#pragma unroll
  for (int r = 0; r < 2; r++) {
    int b = m0 + blq + r * 16;
    c0r[r] = A.c0buf[b * 512 + d];
    c1r[r] = A.c1buf[b * 512 + d];
  }

  short8 stg[8];
  for (int t = 0; t < 256; t++) {
    const int p = t & 1;
    const short* h0p = p ? A.h0b : A.h0a;
    short* h0n       = p ? A.h0a : A.h0b;
    const short* h1p = p ? A.h1b : A.h1a;
    short* h1n       = p ? A.h1a : A.h1b;
    const short* xt = A.xemb + (long)t * (256 * 512);
    const short8* w0 = t ? b0B_0 : b0A_0;
    const short8* w1 = t ? b0B_1 : b0A_1;

    // ---- phase A: LSTM0 gates = [x | h0 | h1-fold] @ B0 ----
    // h0p(t-1) is guarded by a_{t-1}, which this block passed in phase B of
    // t-1 -> safe to read immediately (coherent, no wait).
    stage_issue(stg, h0p, m0, tid);
    floatx4 acc0 = {0.f, 0.f, 0.f, 0.f}, acc1 = {0.f, 0.f, 0.f, 0.f};
    gseg<16>(acc0, acc1, xt, 512, grow, kgrp, w0, w1, 0);     // x (cached)
    vmem_drain();
    stage_write(lds0, stg, tid);
    __syncthreads();
    gsegL<16>(acc0, acc1, lds0, lrowb, swz, kgrp, w0, w1, 16); // h0 (LDS)
    float bA[4];
    if (t == 0) {
      stage_issue(stg, h1p, m0, tid);   // h1 init (for phase B), no wait
      gseg<2>(acc0, acc1, A.pred0pad, 64, grow, kgrp, w0, w1, 32);
      vmem_drain();
      stage_write(lds1, stg, tid);
      __syncthreads();
#pragma unroll
      for (int g = 0; g < 4; g++) bA[g] = A.bias0A[n0 + dl * 4 + g];
    } else {
      bar_wait(gbar + 2 * t - 1);       // b_{t-1}: h1p ready
      stage_issue(stg, h1p, m0, tid);
      vmem_drain();
      stage_write(lds1, stg, tid);
      __syncthreads();
      gsegL<16>(acc0, acc1, lds1, lrowb, swz, kgrp, w0, w1, 32); // fold
#pragma unroll
      for (int g = 0; g < 4; g++) bA[g] = bias0r[g];
    }
#pragma unroll
    for (int r = 0; r < 4; r++) {
      gsm[crow + r][ccol] = acc0[r];
      gsm[crow + r][ccol + 16] = acc1[r];
    }
    __syncthreads();
#pragma unroll
    for (int r = 0; r < 2; r++) {
      int bl = blq + r * 16;
      int b = m0 + bl;
      float gi = gsm[bl][dl * 4 + 0] + bA[0];
      float gf = gsm[bl][dl * 4 + 1] + bA[1];
      float gg = gsm[bl][dl * 4 + 2] + bA[2];
      float go = gsm[bl][dl * 4 + 3] + bA[3];
      float is = 1.f / (1.f + __expf(-gi));
      float fs = 1.f / (1.f + __expf(-gf));
      float os = 1.f / (1.f + __expf(-go));
      float gt = tanhf(gg);
      float cn = fs * c0r[r] + is * gt;
      c0r[r] = cn;
      float hn = os * tanhf(cn);
      st2_coh(h0n + b * 512 + d, (unsigned)(unsigned short)f2bf(hn));
    }
    bar_arrive(gbar + 2 * t);                                   // a_t

    // ---- phase B: LSTM1 gates = [h0_new | h1_prev] @ B1 ----
    floatx4 p0 = {0.f, 0.f, 0.f, 0.f}, p1 = {0.f, 0.f, 0.f, 0.f};
    bar_wait(gbar + 2 * t);                                     // a_t
    stage_issue(stg, h0n, m0, tid);                             // in flight...
    gsegL<16>(p0, p1, lds1, lrowb, swz, kgrp, b1_0, b1_1, 16);  // Whh1*h1p (LDS, hides load latency)
    vmem_drain();
    stage_write(lds0, stg, tid);
    __syncthreads();
    gsegL<16>(p0, p1, lds0, lrowb, swz, kgrp, b1_0, b1_1, 0);   // Wih1*h0n
#pragma unroll
    for (int r = 0; r < 4; r++) {
      gsm[crow + r][ccol] = p0[r];
      gsm[crow + r][ccol + 16] = p1[r];
    }
    __syncthreads();
    float* ctx_t = A.ctx + (long)t * CTX;
#pragma unroll
    for (int r = 0; r < 2; r++) {
      int bl = blq + r * 16;
      int b = m0 + bl;
      float gi = gsm[bl][dl * 4 + 0] + bias1r[0];
      float gf = gsm[bl][dl * 4 + 1] + bias1r[1];
      float gg = gsm[bl][dl * 4 + 2] + bias1r[2];
      float go = gsm[bl][dl * 4 + 3] + bias1r[3];
      float is = 1.f / (1.f + __expf(-gi));
      float fs = 1.f / (1.f + __expf(-gf));
      float os = 1.f / (1.f + __expf(-go));
      float gt = tanhf(gg);
      float cn = fs * c1r[r] + is * gt;
      c1r[r] = cn;
      float hn = os * tanhf(cn);
      st2_coh(h1n + b * 512 + d, (unsigned)(unsigned short)f2bf(hn));
      ctx_t[(long)b * (256L * CTX) + d] = hn;   // plain store; flushed at kernel end
    }
    if (t < 255) bar_arrive(gbar + 2 * t + 1);                  // b_t
  }
}

extern "C" void kernel_launch(void* const* d_in, const int* in_sizes, int n_in,
                              void* d_out, int out_size, void* d_ws, size_t ws_size,
                              hipStream_t stream)
{
  const float* x       = (const float*)d_in[0];
  const float* init_p  = (const float*)d_in[1];
  const float* embed_W = (const float*)d_in[2];
  const float* embed_b = (const float*)d_in[3];
  const float* ni_W1   = (const float*)d_in[4];
  const float* ni_b1   = (const float*)d_in[5];
  const float* ni_W2   = (const float*)d_in[6];
  const float* ni_b2   = (const float*)d_in[7];
  const float* ni_W3   = (const float*)d_in[8];
  const float* ni_b3   = (const float*)d_in[9];
  const float* Wih0    = (const float*)d_in[10];
  const float* Whh0    = (const float*)d_in[11];
  const float* bih0    = (const float*)d_in[12];
  const float* bhh0    = (const float*)d_in[13];
  const float* Wih1    = (const float*)d_in[14];
  const float* Whh1    = (const float*)d_in[15];
  const float* bih1    = (const float*)d_in[16];
  const float* bhh1    = (const float*)d_in[17];
  const float* dec_W   = (const float*)d_in[18];
  const float* dec_b   = (const float*)d_in[19];
  float* out = (float*)d_out;
  char* ws = (char*)d_ws;

  // workspace layout (all 256B-aligned)
  short* xemb = (short*)(ws + 0);                 // [F][B][512] bf16, 67108864 B
  short* B0A  = (short*)(ws + 67108864);          // 1088*2048*2
  short* B0B  = (short*)(ws + 71565312);          // 1536*2048*2
  short* B1p  = (short*)(ws + 77856768);          // 1024*2048*2
  short* Sh0[2] = { (short*)(ws + 82051072), (short*)(ws + 82575360) };
  short* Sh1[2] = { (short*)(ws + 82313216), (short*)(ws + 82837504) };
  float* c0     = (float*)(ws + 83099648);
  float* c1     = (float*)(ws + 83623936);
  float* bias0A = (float*)(ws + 84148224);
  float* bias0B = (float*)(ws + 84156416);
  float* bias1  = (float*)(ws + 84164608);
  short* pred0pad = (short*)(ws + 84172800);      // [256][64] bf16
  float* z1 = (float*)(ws + 84205568);
  float* z2 = (float*)(ws + 84729856);
  unsigned* bar = (unsigned*)(ws + 85778432);     // 8 groups x 512 counters
  (void)in_sizes; (void)n_in; (void)out_size; (void)ws_size;

  // ---- one-time prep (re-run every call; ws is re-poisoned by harness) ----
  pack_b<<<8704, 256, 0, stream>>>(B0A, 34, 0, Wih0, Whh0, Wih1, Whh1, dec_W);
  pack_b<<<12288, 256, 0, stream>>>(B0B, 48, 1, Wih0, Whh0, Wih1, Whh1, dec_W);
  pack_b<<<8192, 256, 0, stream>>>(B1p, 32, 2, Wih0, Whh0, Wih1, Whh1, dec_W);
  prep_small<<<64, 256, 0, stream>>>(bias0A, bias0B, bias1, pred0pad, bar,
                                     bih0, bhh0, bih1, bhh1, Wih0, dec_b, init_p);
  // x_emb = x @ embed_W + embed_b  -> bf16 [F][B][512]
  gemm_f32<<<dim3(8, 1024), 256, 0, stream>>>(x, 34, embed_W, embed_b,
      65536, 512, 34, 1, nullptr, nullptr, xemb, nullptr, nullptr, nullptr);
  // init MLP: z1 = relu(init@W1+b1); z2 = relu(z1@W2+b2); z3 = z2@W3+b3 -> h/c scatter
  gemm_f32<<<dim3(8, 4), 256, 0, stream>>>(init_p, 85, ni_W1, ni_b1,
      256, 512, 85, 0, z1, nullptr, nullptr, nullptr, nullptr, nullptr);
  gemm_f32<<<dim3(16, 4), 256, 0, stream>>>(z1, 512, ni_W2, ni_b2,
      256, 1024, 512, 0, z2, nullptr, nullptr, nullptr, nullptr, nullptr);
  gemm_f32<<<dim3(32, 4), 256, 0, stream>>>(z2, 1024, ni_W3, ni_b3,
      256, 2048, 1024, 2, nullptr, nullptr, Sh0[0], Sh1[0], c0, c1);

  // ---- persistent scan: ONE plain kernel, 256 blocks (1/CU, co-resident) ----
  ScanArgs sa;
  sa.B0A = B0A; sa.B0B = B0B; sa.B1 = B1p;
  sa.bias0A = bias0A; sa.bias0B = bias0B; sa.bias1 = bias1;
  sa.xemb = xemb; sa.pred0pad = pred0pad;
  sa.h0a = Sh0[0]; sa.h0b = Sh0[1]; sa.h1a = Sh1[0]; sa.h1b = Sh1[1];
  sa.c0buf = c0; sa.c1buf = c1;
  sa.ctx = out + CTXOFF; sa.bar = bar;
  scan_kernel<<<256, 256, 0, stream>>>(sa);

  // ---- preds = ctx @ dec_W + dec_b -> pred_kp3d + motion_context[...,512:] ----
  gemm_f32<<<dim3(1, 1024), 256, 0, stream>>>(out + CTXOFF, CTX, dec_W, dec_b,
      65536, NJ3, 512, 3, out, out + CTXOFF, nullptr, nullptr, nullptr, nullptr);
}

// Round 4
// 4215.218 us; speedup vs baseline: 2.1732x; 1.1696x over previous
//
#include <hip/hip_runtime.h>

#define B_N 256
#define F_N 256
#define NJ3 51
#define DH 512
#define G4 2048
#define CTX 563
#define OUT0 (B_N * F_N * NJ3)   // 3342336
#define CTXOFF OUT0
#define GRPN 32u                  // blocks per barrier group (one mt = 32 ng-slices)

typedef __attribute__((ext_vector_type(8))) short short8;
typedef __attribute__((ext_vector_type(4))) float floatx4;

__device__ __forceinline__ short f2bf(float f) {
  unsigned u = __float_as_uint(f);
  u = (u + 0x7fffu + ((u >> 16) & 1u)) >> 16;
  return (short)u;
}

// ---------------------------------------------------------------------------
// Generic fp32 tiled GEMM (unchanged): C = act(A[M,K](lda) @ Bw[K,N] + bias)
// ---------------------------------------------------------------------------
__global__ __launch_bounds__(256) void gemm_f32(
    const float* __restrict__ A, int lda,
    const float* __restrict__ Bw, const float* __restrict__ bias,
    int M, int N, int K, int mode,
    float* __restrict__ out_f, float* __restrict__ out_f2,
    short* __restrict__ out_h0, short* __restrict__ out_h1,
    float* __restrict__ out_c0, float* __restrict__ out_c1)
{
  __shared__ float As[16][64];
  __shared__ float Bs[16][68];
  int tid = threadIdx.x;
  int n0 = blockIdx.x * 64, m0 = blockIdx.y * 64;
  float acc[4][4] = {{0.f}};
  int ar = tid >> 2, ak = (tid & 3) * 4;
  int bk = tid >> 6, bn = tid & 63;
  int tm = (tid >> 4) * 4, tn = (tid & 15) * 4;
  for (int k0 = 0; k0 < K; k0 += 16) {
#pragma unroll
    for (int i = 0; i < 4; i++) {
      int kk = ak + i;
      float v = 0.f;
      if (k0 + kk < K) v = A[(long)(m0 + ar) * lda + k0 + kk];
      As[kk][ar] = v;
    }
#pragma unroll
    for (int i = 0; i < 4; i++) {
      int kk = bk + i * 4;
      float v = 0.f;
      if (k0 + kk < K && n0 + bn < N) v = Bw[(long)(k0 + kk) * N + n0 + bn];
      Bs[kk][bn] = v;
    }
    __syncthreads();
#pragma unroll
    for (int kk = 0; kk < 16; kk++) {
      float a0[4], b0[4];
#pragma unroll
      for (int i = 0; i < 4; i++) a0[i] = As[kk][tm + i];
#pragma unroll
      for (int j = 0; j < 4; j++) b0[j] = Bs[kk][tn + j];
#pragma unroll
      for (int i = 0; i < 4; i++)
#pragma unroll
        for (int j = 0; j < 4; j++) acc[i][j] += a0[i] * b0[j];
    }
    __syncthreads();
  }
#pragma unroll
  for (int i = 0; i < 4; i++) {
    int m = m0 + tm + i;
#pragma unroll
    for (int j = 0; j < 4; j++) {
      int n = n0 + tn + j;
      if (n >= N) continue;
      float v = acc[i][j] + bias[n];
      if (mode == 0) {
        out_f[(long)m * N + n] = fmaxf(v, 0.f);
      } else if (mode == 1) {
        int b = m >> 8, f = m & 255;
        out_h0[((long)f * 256 + b) * 512 + n] = f2bf(v);
      } else if (mode == 2) {
        int d = n & 511;
        if (n < 512)       out_h0[m * 512 + d] = f2bf(v);
        else if (n < 1024) out_h1[m * 512 + d] = f2bf(v);
        else if (n < 1536) out_c0[m * 512 + d] = v;
        else               out_c1[m * 512 + d] = v;
      } else {
        out_f[(long)m * NJ3 + n] = v;
        out_f2[(long)m * CTX + 512 + n] = v;
      }
    }
  }
}

// ---------------------------------------------------------------------------
// Pack weights (fp32 -> bf16) into exact MFMA B-fragment layout (unchanged;
// mode 0 now packed with KC=36 -> zero rows for k in [1088,1152))
// ---------------------------------------------------------------------------
__global__ __launch_bounds__(256) void pack_b(
    short* __restrict__ dst, int KC, int mode,
    const float* __restrict__ Wih0, const float* __restrict__ Whh0,
    const float* __restrict__ Wih1, const float* __restrict__ Whh1,
    const float* __restrict__ dec_W)
{
  int idx = blockIdx.x * 256 + threadIdx.x;
  int total = KC * 32 * G4;
  if (idx >= total) return;
  int j = idx & 7;
  int l = (idx >> 3) & 63;
  int tt = idx >> 9;
  int kc = tt % KC;
  int nt = tt / KC;
  int k = kc * 32 + ((l >> 4) << 3) + j;
  int jp = nt * 16 + (l & 15);
  int jo = ((jp & 3) << 9) + (jp >> 2);
  float v = 0.f;
  if (mode == 0) {
    if (k < 512) v = Wih0[jo * 563 + k];
    else if (k < 1024) v = Whh0[jo * 512 + k - 512];
    else { int p = k - 1024; v = (p < NJ3) ? Wih0[jo * 563 + 512 + p] : 0.f; }
  } else if (mode == 1) {
    if (k < 512) v = Wih0[jo * 563 + k];
    else if (k < 1024) v = Whh0[jo * 512 + k - 512];
    else {
      int dd = k - 1024;
      float s = 0.f;
      for (int p = 0; p < NJ3; p++) s += dec_W[dd * NJ3 + p] * Wih0[jo * 563 + 512 + p];
      v = s;
    }
  } else {
    if (k < 512) v = Wih1[jo * 512 + k];
    else v = Whh1[jo * 512 + k - 512];
  }
  dst[idx] = f2bf(v);
}

// biases in j'=4d+g order; bias0B includes dec_b fold; pred0pad bf16 [256][128];
// zeroes the 8*512 group-barrier counters.
__global__ __launch_bounds__(256) void prep_small(
    float* __restrict__ bias0A, float* __restrict__ bias0B, float* __restrict__ bias1,
    short* __restrict__ pred0pad, unsigned* __restrict__ bar,
    const float* __restrict__ bih0, const float* __restrict__ bhh0,
    const float* __restrict__ bih1, const float* __restrict__ bhh1,
    const float* __restrict__ Wih0, const float* __restrict__ dec_b,
    const float* __restrict__ init_p)
{
  int i = blockIdx.x * 256 + threadIdx.x;
  if (i < G4) {
    int jo = ((i & 3) << 9) + (i >> 2);
    float b0 = bih0[jo] + bhh0[jo];
    bias0A[i] = b0;
    float s = 0.f;
    for (int p = 0; p < NJ3; p++) s += dec_b[p] * Wih0[jo * 563 + 512 + p];
    bias0B[i] = b0 + s;
    bias1[i] = bih1[jo] + bhh1[jo];
  }
  if (i < 4096) bar[i] = 0u;
  if (i < 32768) {
    int b = i >> 7, p = i & 127;
    pred0pad[i] = (p < NJ3) ? f2bf(init_p[b * 85 + p]) : (short)0;
  }
}

// ---------------------------------------------------------------------------
// Targeted coherence primitives (proven in r3): h-data via sc0 sc1 (MALL),
// relaxed agent atomics for counters, no cache-wide fences ever.
// ---------------------------------------------------------------------------
__device__ __forceinline__ void ld16_coh(short8* dst, const void* p) {
  asm volatile("global_load_dwordx4 %0, %1, off sc0 sc1"
               : "=v"(*dst) : "v"(p) : "memory");
}
__device__ __forceinline__ void st2_coh(void* p, unsigned v) {
  asm volatile("global_store_short %0, %1, off sc0 sc1"
               :: "v"(p), "v"(v) : "memory");
}
__device__ __forceinline__ void vmem_drain() {
  asm volatile("s_waitcnt vmcnt(0)" ::: "memory");
  __builtin_amdgcn_sched_barrier(0);
}

__device__ __forceinline__ void bar_arrive(unsigned* c) {
  vmem_drain();
  __syncthreads();
  if (threadIdx.x == 0)
    __hip_atomic_fetch_add(c, 1u, __ATOMIC_RELAXED, __HIP_MEMORY_SCOPE_AGENT);
}
__device__ __forceinline__ void bar_wait(unsigned* c) {
  if (threadIdx.x == 0) {
    while (__hip_atomic_load(c, __ATOMIC_RELAXED, __HIP_MEMORY_SCOPE_AGENT) < GRPN)
      __builtin_amdgcn_s_sleep(1);
  }
  __syncthreads();
  __builtin_amdgcn_sched_barrier(0);
}

// Coherent panel staging: 32 KB panel, 512 threads x 4 x 16B.
__device__ __forceinline__ void stage_issue(short8 r[4], const short* src,
                                            int m0, int tid) {
#pragma unroll
  for (int i = 0; i < 4; i++) {
    int e = i * 512 + tid;
    int row = e >> 6, colb = (e & 63) * 16;
    ld16_coh(&r[i], (const char*)src + (long)(m0 + row) * 1024 + colb);
  }
}
__device__ __forceinline__ void stage_write(char* panel, short8 r[4], int tid) {
#pragma unroll
  for (int i = 0; i < 4; i++) {
    int e = i * 512 + tid;
    int row = e >> 6, colb = (e & 63) * 16;
    *(short8*)(panel + row * 1024 + (colb ^ ((row & 7) << 4))) = r[i];
  }
}

struct ScanArgs {
  const short* B0A; const short* B0B; const short* B1;
  const float* bias0A; const float* bias0B; const float* bias1;
  const short* xemb; const short* pred0pad;
  short* h0a; short* h0b; short* h1a; short* h1b;
  const float* c0buf; const float* c1buf;
  float* ctx; unsigned* bar;
};

// ---------------------------------------------------------------------------
// Persistent scan v2: 256 blocks x 512 threads (8 waves = 2/SIMD).
// Wave = (wn col-half) x (kq K-quarter); each wave covers all 32 rows with
// 4 MFMA/kc. ALL steady-state weights live in REGISTERS (w0: 96 VGPR,
// w1: 64 VGPR per wave) -> zero per-step weight memory traffic.
// Split-K partials summed via 4-plane gsm. lds0 carries h0 across the
// phase boundary (phase-B stage of h0n(t) IS phase-A's h0p(t+1)), so only
// 2 coherent panel stages per step (h1p, h0n). kq dependencies: kq0=x only,
// kq3=fold only -> independent MFMA runs before each barrier wait.
// ---------------------------------------------------------------------------
__global__ __launch_bounds__(512) void scan_kernel(ScanArgs A)
{
  __shared__ float gsm[4][32][68];
  __shared__ char lds0[32 * 1024];   // h0 panel (carried A<->B)
  __shared__ char lds1[32 * 1024];   // h1 panel
  const int tid = threadIdx.x;
  const int bid = blockIdx.x;
  const int ng = (bid & 7) + (((bid >> 3) & 3) << 3);
  const int mt = bid >> 5;
  const int m0 = mt * 32, n0 = ng * 64;
  const int lane = tid & 63, wid = tid >> 6;
  const int wn = wid & 1;            // col half (2 nt)
  const int kq = wid >> 1;           // K quarter
  const int kgrp = lane >> 4;
  const int r15 = lane & 15;
  const int r15b = r15 * 1024;
  const int r16b = (r15 + 16) * 1024;
  const int sw = (r15 & 7) << 4;
  const int arow0 = m0 + r15;
  const int erow = tid >> 4;         // epilogue: 0..31
  const int edl = tid & 15;
  const int d = ng * 16 + edl;
  const int eb = m0 + erow;
  unsigned* gbar = A.bar + mt * 512;

  // ---- one-time: weights into registers ----
  const int nt0 = ng * 4 + wn * 2;
  short8 w0[12][2], w1[8][2];
  {
    const short8* B0 = (const short8*)A.B0B;
    const short8* B1 = (const short8*)A.B1;
#pragma unroll
    for (int kc = 0; kc < 12; kc++) {
      w0[kc][0] = B0[((long)nt0 * 48 + kq * 12 + kc) * 64 + lane];
      w0[kc][1] = B0[((long)(nt0 + 1) * 48 + kq * 12 + kc) * 64 + lane];
    }
    const int kqB = kq ^ 2;   // kq0/1 hold h1p-range, kq2/3 hold h0n-range
#pragma unroll
    for (int kc = 0; kc < 8; kc++) {
      w1[kc][0] = B1[((long)nt0 * 32 + kqB * 8 + kc) * 64 + lane];
      w1[kc][1] = B1[((long)(nt0 + 1) * 32 + kqB * 8 + kc) * 64 + lane];
    }
  }
  const short8* bA0 = (const short8*)A.B0A + (long)nt0 * 36 * 64 + lane;
  const short8* bA1 = (const short8*)A.B0A + (long)(nt0 + 1) * 36 * 64 + lane;

  float biasAr[4], bias0r[4], bias1r[4];
#pragma unroll
  for (int g = 0; g < 4; g++) {
    biasAr[g] = A.bias0A[n0 + edl * 4 + g];
    bias0r[g] = A.bias0B[n0 + edl * 4 + g];
    bias1r[g] = A.bias1[n0 + edl * 4 + g];
  }
  float c0r = A.c0buf[eb * 512 + d];
  float c1r = A.c1buf[eb * 512 + d];

  short8 stg[4];
  short8 a0, a1;
  floatx4 acc00, acc01, acc10, acc11;

#define MFMA_ __builtin_amdgcn_mfma_f32_16x16x32_bf16
#define MF4(B0V, B1V) { acc00 = MFMA_(a0, (B0V), acc00, 0, 0, 0); \
                        acc01 = MFMA_(a0, (B1V), acc01, 0, 0, 0); \
                        acc10 = MFMA_(a1, (B0V), acc10, 0, 0, 0); \
                        acc11 = MFMA_(a1, (B1V), acc11, 0, 0, 0); }
#define XLD(c) { a0 = *(const short8*)(xt + (long)arow0 * 512 + (c) * 32 + kgrp * 8); \
                 a1 = *(const short8*)(xt + (long)(arow0 + 16) * 512 + (c) * 32 + kgrp * 8); }
#define LLD(P, cl) { int kb = (cl) * 64 + kgrp * 16; \
                     a0 = *(const short8*)((P) + r15b + (kb ^ sw)); \
                     a1 = *(const short8*)((P) + r16b + (kb ^ sw)); }
#define PLD(cl) { a0 = *(const short8*)(A.pred0pad + (long)arow0 * 128 + (cl) * 32 + kgrp * 8); \
                  a1 = *(const short8*)(A.pred0pad + (long)(arow0 + 16) * 128 + (cl) * 32 + kgrp * 8); }
#define ZACC { acc00 = (floatx4){0.f,0.f,0.f,0.f}; acc01 = acc00; acc10 = acc00; acc11 = acc00; }

  auto gsmw = [&]() {
#pragma unroll
    for (int r = 0; r < 4; r++) {
      gsm[kq][kgrp * 4 + r][wn * 32 + r15] = acc00[r];
      gsm[kq][kgrp * 4 + r][wn * 32 + 16 + r15] = acc01[r];
      gsm[kq][kgrp * 4 + r + 16][wn * 32 + r15] = acc10[r];
      gsm[kq][kgrp * 4 + r + 16][wn * 32 + 16 + r15] = acc11[r];
    }
  };

  for (int t = 0; t < 256; t++) {
    const int p = t & 1;
    const short* h0p = p ? A.h0b : A.h0a;
    short* h0n       = p ? A.h0a : A.h0b;
    const short* h1p = p ? A.h1b : A.h1a;
    short* h1n       = p ? A.h1a : A.h1b;
    const short* xt = A.xemb + (long)t * (256 * 512);

    // ================= phase A: LSTM0 =================
    ZACC;
    if (t == 0) {
      // streamed B0A (KC=36), 9 kc per kq; stage h0p + h1p panels once
      stage_issue(stg, h0p, m0, tid);
      if (kq == 0) {
#pragma unroll
        for (int kc = 0; kc < 9; kc++) { XLD(kc); MF4(bA0[kc * 64], bA1[kc * 64]); }
      } else if (kq == 1) {
#pragma unroll
        for (int kc = 0; kc < 7; kc++) { XLD(9 + kc); MF4(bA0[(9 + kc) * 64], bA1[(9 + kc) * 64]); }
      }
      vmem_drain(); stage_write(lds0, stg, tid); __syncthreads();
      if (kq == 1) {
#pragma unroll
        for (int kc = 0; kc < 2; kc++) { LLD(lds0, kc); MF4(bA0[(16 + kc) * 64], bA1[(16 + kc) * 64]); }
      } else if (kq == 2) {
#pragma unroll
        for (int kc = 0; kc < 9; kc++) { LLD(lds0, 2 + kc); MF4(bA0[(18 + kc) * 64], bA1[(18 + kc) * 64]); }
      } else if (kq == 3) {
#pragma unroll
        for (int kc = 0; kc < 5; kc++) { LLD(lds0, 11 + kc); MF4(bA0[(27 + kc) * 64], bA1[(27 + kc) * 64]); }
      }
      stage_issue(stg, h1p, m0, tid);
      if (kq == 3) {
#pragma unroll
        for (int kc = 0; kc < 4; kc++) { PLD(kc); MF4(bA0[(32 + kc) * 64], bA1[(32 + kc) * 64]); }
      }
      vmem_drain(); stage_write(lds1, stg, tid); __syncthreads();
    } else {
      // independent work first: x (global) + h0 (carried in lds0 from phase B)
      if (kq == 0) {
#pragma unroll
        for (int kc = 0; kc < 12; kc++) { XLD(kc); MF4(w0[kc][0], w0[kc][1]); }
      } else if (kq == 1) {
#pragma unroll
        for (int kc = 0; kc < 4; kc++) { XLD(12 + kc); MF4(w0[kc][0], w0[kc][1]); }
#pragma unroll
        for (int kc = 4; kc < 12; kc++) { LLD(lds0, kc - 4); MF4(w0[kc][0], w0[kc][1]); }
      } else if (kq == 2) {
#pragma unroll
        for (int kc = 0; kc < 8; kc++) { LLD(lds0, 8 + kc); MF4(w0[kc][0], w0[kc][1]); }
      }
      bar_wait(gbar + 2 * t - 1);            // b_{t-1}: h1p ready
      stage_issue(stg, h1p, m0, tid);
      vmem_drain(); stage_write(lds1, stg, tid); __syncthreads();
      if (kq == 2) {
#pragma unroll
        for (int kc = 8; kc < 12; kc++) { LLD(lds1, kc - 8); MF4(w0[kc][0], w0[kc][1]); }
      } else if (kq == 3) {
#pragma unroll
        for (int kc = 0; kc < 12; kc++) { LLD(lds1, 4 + kc); MF4(w0[kc][0], w0[kc][1]); }
      }
    }
    gsmw();
    __syncthreads();
    {
      floatx4 s = *(const floatx4*)&gsm[0][erow][edl * 4];
#pragma unroll
      for (int pl = 1; pl < 4; pl++) {
        floatx4 q = *(const floatx4*)&gsm[pl][erow][edl * 4];
        s[0] += q[0]; s[1] += q[1]; s[2] += q[2]; s[3] += q[3];
      }
      const float* bA = t ? bias0r : biasAr;
      float gi = s[0] + bA[0], gf = s[1] + bA[1], gg = s[2] + bA[2], go = s[3] + bA[3];
      float is = 1.f / (1.f + __expf(-gi));
      float fs = 1.f / (1.f + __expf(-gf));
      float os = 1.f / (1.f + __expf(-go));
      float gt = tanhf(gg);
      float cn = fs * c0r + is * gt;
      c0r = cn;
      float hn = os * tanhf(cn);
      st2_coh(h0n + eb * 512 + d, (unsigned)(unsigned short)f2bf(hn));
    }
    bar_arrive(gbar + 2 * t);                // a_t

    // ================= phase B: LSTM1 =================
    ZACC;
    // independent: Whh1 x h1p from lds1 (kq0/1 hold that weight range)
    if (kq == 0) {
#pragma unroll
      for (int kc = 0; kc < 8; kc++) { LLD(lds1, kc); MF4(w1[kc][0], w1[kc][1]); }
    } else if (kq == 1) {
#pragma unroll
      for (int kc = 0; kc < 8; kc++) { LLD(lds1, 8 + kc); MF4(w1[kc][0], w1[kc][1]); }
    }
    bar_wait(gbar + 2 * t);                  // a_t: h0n ready
    stage_issue(stg, h0n, m0, tid);
    vmem_drain(); stage_write(lds0, stg, tid); __syncthreads();
    if (kq == 2) {
#pragma unroll
      for (int kc = 0; kc < 8; kc++) { LLD(lds0, kc); MF4(w1[kc][0], w1[kc][1]); }
    } else if (kq == 3) {
#pragma unroll
      for (int kc = 0; kc < 8; kc++) { LLD(lds0, 8 + kc); MF4(w1[kc][0], w1[kc][1]); }
    }
    gsmw();
    __syncthreads();
    {
      floatx4 s = *(const floatx4*)&gsm[0][erow][edl * 4];
#pragma unroll
      for (int pl = 1; pl < 4; pl++) {
        floatx4 q = *(const floatx4*)&gsm[pl][erow][edl * 4];
        s[0] += q[0]; s[1] += q[1]; s[2] += q[2]; s[3] += q[3];
      }
      float gi = s[0] + bias1r[0], gf = s[1] + bias1r[1];
      float gg = s[2] + bias1r[2], go = s[3] + bias1r[3];
      float is = 1.f / (1.f + __expf(-gi));
      float fs = 1.f / (1.f + __expf(-gf));
      float os = 1.f / (1.f + __expf(-go));
      float gt = tanhf(gg);
      float cn = fs * c1r + is * gt;
      c1r = cn;
      float hn = os * tanhf(cn);
      st2_coh(h1n + eb * 512 + d, (unsigned)(unsigned short)f2bf(hn));
      (A.ctx + (long)t * CTX)[(long)eb * (256L * CTX) + d] = hn;
    }
    if (t < 255) bar_arrive(gbar + 2 * t + 1);   // b_t
  }
}

extern "C" void kernel_launch(void* const* d_in, const int* in_sizes, int n_in,
                              void* d_out, int out_size, void* d_ws, size_t ws_size,
                              hipStream_t stream)
{
  const float* x       = (const float*)d_in[0];
  const float* init_p  = (const float*)d_in[1];
  const float* embed_W = (const float*)d_in[2];
  const float* embed_b = (const float*)d_in[3];
  const float* ni_W1   = (const float*)d_in[4];
  const float* ni_b1   = (const float*)d_in[5];
  const float* ni_W2   = (const float*)d_in[6];
  const float* ni_b2   = (const float*)d_in[7];
  const float* ni_W3   = (const float*)d_in[8];
  const float* ni_b3   = (const float*)d_in[9];
  const float* Wih0    = (const float*)d_in[10];
  const float* Whh0    = (const float*)d_in[11];
  const float* bih0    = (const float*)d_in[12];
  const float* bhh0    = (const float*)d_in[13];
  const float* Wih1    = (const float*)d_in[14];
  const float* Whh1    = (const float*)d_in[15];
  const float* bih1    = (const float*)d_in[16];
  const float* bhh1    = (const float*)d_in[17];
  const float* dec_W   = (const float*)d_in[18];
  const float* dec_b   = (const float*)d_in[19];
  float* out = (float*)d_out;
  char* ws = (char*)d_ws;

  // workspace layout (all 256B-aligned), ~86.1 MB
  short* xemb = (short*)(ws + 0);                 // [F][B][512] bf16, 67108864
  short* B0A  = (short*)(ws + 67108864);          // 36*32*2048*2 = 4718592
  short* B0B  = (short*)(ws + 71827456);          // 48*32*2048*2 = 6291456
  short* B1p  = (short*)(ws + 78118912);          // 32*32*2048*2 = 4194304
  short* Sh0[2] = { (short*)(ws + 82313216), (short*)(ws + 82575360) };
  short* Sh1[2] = { (short*)(ws + 82837504), (short*)(ws + 83099648) };
  float* c0     = (float*)(ws + 83361792);
  float* c1     = (float*)(ws + 83886080);
  float* bias0A = (float*)(ws + 84410368);
  float* bias0B = (float*)(ws + 84418560);
  float* bias1  = (float*)(ws + 84426752);
  short* pred0pad = (short*)(ws + 84434944);      // [256][128] bf16, 65536
  float* z1 = (float*)(ws + 84500480);
  float* z2 = (float*)(ws + 85024768);
  unsigned* bar = (unsigned*)(ws + 86073344);     // 8 groups x 512 counters
  (void)in_sizes; (void)n_in; (void)out_size; (void)ws_size;

  // ---- one-time prep (re-run every call; ws is re-poisoned by harness) ----
  pack_b<<<9216, 256, 0, stream>>>(B0A, 36, 0, Wih0, Whh0, Wih1, Whh1, dec_W);
  pack_b<<<12288, 256, 0, stream>>>(B0B, 48, 1, Wih0, Whh0, Wih1, Whh1, dec_W);
  pack_b<<<8192, 256, 0, stream>>>(B1p, 32, 2, Wih0, Whh0, Wih1, Whh1, dec_W);
  prep_small<<<128, 256, 0, stream>>>(bias0A, bias0B, bias1, pred0pad, bar,
                                      bih0, bhh0, bih1, bhh1, Wih0, dec_b, init_p);
  // x_emb = x @ embed_W + embed_b  -> bf16 [F][B][512]
  gemm_f32<<<dim3(8, 1024), 256, 0, stream>>>(x, 34, embed_W, embed_b,
      65536, 512, 34, 1, nullptr, nullptr, xemb, nullptr, nullptr, nullptr);
  // init MLP: z1 = relu(init@W1+b1); z2 = relu(z1@W2+b2); z3 = z2@W3+b3 -> h/c scatter
  gemm_f32<<<dim3(8, 4), 256, 0, stream>>>(init_p, 85, ni_W1, ni_b1,
      256, 512, 85, 0, z1, nullptr, nullptr, nullptr, nullptr, nullptr);
  gemm_f32<<<dim3(16, 4), 256, 0, stream>>>(z1, 512, ni_W2, ni_b2,
      256, 1024, 512, 0, z2, nullptr, nullptr, nullptr, nullptr, nullptr);
  gemm_f32<<<dim3(32, 4), 256, 0, stream>>>(z2, 1024, ni_W3, ni_b3,
      256, 2048, 1024, 2, nullptr, nullptr, Sh0[0], Sh1[0], c0, c1);

  // ---- persistent scan: ONE plain kernel, 256 blocks x 512 thr (1/CU) ----
  ScanArgs sa;
  sa.B0A = B0A; sa.B0B = B0B; sa.B1 = B1p;
  sa.bias0A = bias0A; sa.bias0B = bias0B; sa.bias1 = bias1;
  sa.xemb = xemb; sa.pred0pad = pred0pad;
  sa.h0a = Sh0[0]; sa.h0b = Sh0[1]; sa.h1a = Sh1[0]; sa.h1b = Sh1[1];
  sa.c0buf = c0; sa.c1buf = c1;
  sa.ctx = out + CTXOFF; sa.bar = bar;
  scan_kernel<<<256, 512, 0, stream>>>(sa);

  // ---- preds = ctx @ dec_W + dec_b -> pred_kp3d + motion_context[...,512:] ----
  gemm_f32<<<dim3(1, 1024), 256, 0, stream>>>(out + CTXOFF, CTX, dec_W, dec_b,
      65536, NJ3, 512, 3, out, out + CTXOFF, nullptr, nullptr, nullptr, nullptr);
}

// Round 5
// 4209.261 us; speedup vs baseline: 2.1762x; 1.0014x over previous
//
#include <hip/hip_runtime.h>

#define B_N 256
#define F_N 256
#define NJ3 51
#define DH 512
#define G4 2048
#define CTX 563
#define OUT0 (B_N * F_N * NJ3)   // 3342336
#define CTXOFF OUT0
#define GRPN 32u                  // blocks per barrier group (one mt = 32 ng-slices)

typedef __attribute__((ext_vector_type(8))) short short8;
typedef __attribute__((ext_vector_type(4))) float floatx4;

__device__ __forceinline__ short f2bf(float f) {
  unsigned u = __float_as_uint(f);
  u = (u + 0x7fffu + ((u >> 16) & 1u)) >> 16;
  return (short)u;
}

// ---------------------------------------------------------------------------
// Generic fp32 tiled GEMM (unchanged): C = act(A[M,K](lda) @ Bw[K,N] + bias)
// ---------------------------------------------------------------------------
__global__ __launch_bounds__(256) void gemm_f32(
    const float* __restrict__ A, int lda,
    const float* __restrict__ Bw, const float* __restrict__ bias,
    int M, int N, int K, int mode,
    float* __restrict__ out_f, float* __restrict__ out_f2,
    short* __restrict__ out_h0, short* __restrict__ out_h1,
    float* __restrict__ out_c0, float* __restrict__ out_c1)
{
  __shared__ float As[16][64];
  __shared__ float Bs[16][68];
  int tid = threadIdx.x;
  int n0 = blockIdx.x * 64, m0 = blockIdx.y * 64;
  float acc[4][4] = {{0.f}};
  int ar = tid >> 2, ak = (tid & 3) * 4;
  int bk = tid >> 6, bn = tid & 63;
  int tm = (tid >> 4) * 4, tn = (tid & 15) * 4;
  for (int k0 = 0; k0 < K; k0 += 16) {
#pragma unroll
    for (int i = 0; i < 4; i++) {
      int kk = ak + i;
      float v = 0.f;
      if (k0 + kk < K) v = A[(long)(m0 + ar) * lda + k0 + kk];
      As[kk][ar] = v;
    }
#pragma unroll
    for (int i = 0; i < 4; i++) {
      int kk = bk + i * 4;
      float v = 0.f;
      if (k0 + kk < K && n0 + bn < N) v = Bw[(long)(k0 + kk) * N + n0 + bn];
      Bs[kk][bn] = v;
    }
    __syncthreads();
#pragma unroll
    for (int kk = 0; kk < 16; kk++) {
      float a0[4], b0[4];
#pragma unroll
      for (int i = 0; i < 4; i++) a0[i] = As[kk][tm + i];
#pragma unroll
      for (int j = 0; j < 4; j++) b0[j] = Bs[kk][tn + j];
#pragma unroll
      for (int i = 0; i < 4; i++)
#pragma unroll
        for (int j = 0; j < 4; j++) acc[i][j] += a0[i] * b0[j];
    }
    __syncthreads();
  }
#pragma unroll
  for (int i = 0; i < 4; i++) {
    int m = m0 + tm + i;
#pragma unroll
    for (int j = 0; j < 4; j++) {
      int n = n0 + tn + j;
      if (n >= N) continue;
      float v = acc[i][j] + bias[n];
      if (mode == 0) {
        out_f[(long)m * N + n] = fmaxf(v, 0.f);
      } else if (mode == 1) {
        int b = m >> 8, f = m & 255;
        out_h0[((long)f * 256 + b) * 512 + n] = f2bf(v);
      } else if (mode == 2) {
        int d = n & 511;
        if (n < 512)       out_h0[m * 512 + d] = f2bf(v);
        else if (n < 1024) out_h1[m * 512 + d] = f2bf(v);
        else if (n < 1536) out_c0[m * 512 + d] = v;
        else               out_c1[m * 512 + d] = v;
      } else {
        out_f[(long)m * NJ3 + n] = v;
        out_f2[(long)m * CTX + 512 + n] = v;
      }
    }
  }
}

// ---------------------------------------------------------------------------
// Pack weights (fp32 -> bf16) into exact MFMA B-fragment layout (unchanged;
// mode 0 packed with KC=36 -> zero rows for k in [1088,1152))
// ---------------------------------------------------------------------------
__global__ __launch_bounds__(256) void pack_b(
    short* __restrict__ dst, int KC, int mode,
    const float* __restrict__ Wih0, const float* __restrict__ Whh0,
    const float* __restrict__ Wih1, const float* __restrict__ Whh1,
    const float* __restrict__ dec_W)
{
  int idx = blockIdx.x * 256 + threadIdx.x;
  int total = KC * 32 * G4;
  if (idx >= total) return;
  int j = idx & 7;
  int l = (idx >> 3) & 63;
  int tt = idx >> 9;
  int kc = tt % KC;
  int nt = tt / KC;
  int k = kc * 32 + ((l >> 4) << 3) + j;
  int jp = nt * 16 + (l & 15);
  int jo = ((jp & 3) << 9) + (jp >> 2);
  float v = 0.f;
  if (mode == 0) {
    if (k < 512) v = Wih0[jo * 563 + k];
    else if (k < 1024) v = Whh0[jo * 512 + k - 512];
    else { int p = k - 1024; v = (p < NJ3) ? Wih0[jo * 563 + 512 + p] : 0.f; }
  } else if (mode == 1) {
    if (k < 512) v = Wih0[jo * 563 + k];
    else if (k < 1024) v = Whh0[jo * 512 + k - 512];
    else {
      int dd = k - 1024;
      float s = 0.f;
      for (int p = 0; p < NJ3; p++) s += dec_W[dd * NJ3 + p] * Wih0[jo * 563 + 512 + p];
      v = s;
    }
  } else {
    if (k < 512) v = Wih1[jo * 512 + k];
    else v = Whh1[jo * 512 + k - 512];
  }
  dst[idx] = f2bf(v);
}

// biases in j'=4d+g order; bias0B includes dec_b fold; pred0pad bf16 [256][128];
// zeroes the 8*512 group-barrier counters.
__global__ __launch_bounds__(256) void prep_small(
    float* __restrict__ bias0A, float* __restrict__ bias0B, float* __restrict__ bias1,
    short* __restrict__ pred0pad, unsigned* __restrict__ bar,
    const float* __restrict__ bih0, const float* __restrict__ bhh0,
    const float* __restrict__ bih1, const float* __restrict__ bhh1,
    const float* __restrict__ Wih0, const float* __restrict__ dec_b,
    const float* __restrict__ init_p)
{
  int i = blockIdx.x * 256 + threadIdx.x;
  if (i < G4) {
    int jo = ((i & 3) << 9) + (i >> 2);
    float b0 = bih0[jo] + bhh0[jo];
    bias0A[i] = b0;
    float s = 0.f;
    for (int p = 0; p < NJ3; p++) s += dec_b[p] * Wih0[jo * 563 + 512 + p];
    bias0B[i] = b0 + s;
    bias1[i] = bih1[jo] + bhh1[jo];
  }
  if (i < 4096) bar[i] = 0u;
  if (i < 32768) {
    int b = i >> 7, p = i & 127;
    pred0pad[i] = (p < NJ3) ? f2bf(init_p[b * 85 + p]) : (short)0;
  }
}

// ---------------------------------------------------------------------------
// Targeted coherence primitives (proven in r3): h-data via sc0 sc1 (MALL),
// relaxed agent atomics for counters, no cache-wide fences ever.
// ---------------------------------------------------------------------------
__device__ __forceinline__ void ld16_coh(short8* dst, const void* p) {
  asm volatile("global_load_dwordx4 %0, %1, off sc0 sc1"
               : "=v"(*dst) : "v"(p) : "memory");
}
__device__ __forceinline__ void st2_coh(void* p, unsigned v) {
  asm volatile("global_store_short %0, %1, off sc0 sc1"
               :: "v"(p), "v"(v) : "memory");
}
__device__ __forceinline__ void vmem_drain() {
  asm volatile("s_waitcnt vmcnt(0)" ::: "memory");
  __builtin_amdgcn_sched_barrier(0);
}

__device__ __forceinline__ void bar_arrive(unsigned* c) {
  vmem_drain();
  __syncthreads();
  if (threadIdx.x == 0)
    __hip_atomic_fetch_add(c, 1u, __ATOMIC_RELAXED, __HIP_MEMORY_SCOPE_AGENT);
}
__device__ __forceinline__ void bar_wait(unsigned* c) {
  if (threadIdx.x == 0) {
    while (__hip_atomic_load(c, __ATOMIC_RELAXED, __HIP_MEMORY_SCOPE_AGENT) < GRPN)
      __builtin_amdgcn_s_sleep(1);
  }
  __syncthreads();
  __builtin_amdgcn_sched_barrier(0);
}

// Coherent panel staging: 32 KB panel, 512 threads x 4 x 16B.
__device__ __forceinline__ void stage_issue(short8 r[4], const short* src,
                                            int m0, int tid) {
#pragma unroll
  for (int i = 0; i < 4; i++) {
    int e = i * 512 + tid;
    int row = e >> 6, colb = (e & 63) * 16;
    ld16_coh(&r[i], (const char*)src + (long)(m0 + row) * 1024 + colb);
  }
}
__device__ __forceinline__ void stage_write(char* panel, short8 r[4], int tid) {
#pragma unroll
  for (int i = 0; i < 4; i++) {
    int e = i * 512 + tid;
    int row = e >> 6, colb = (e & 63) * 16;
    *(short8*)(panel + row * 1024 + (colb ^ ((row & 7) << 4))) = r[i];
  }
}

struct ScanArgs {
  const short* B0A; const short* B0B; const short* B1;
  const float* bias0A; const float* bias0B; const float* bias1;
  const short* xemb; const short* pred0pad;
  short* h0a; short* h0b; short* h1a; short* h1b;
  const float* c0buf; const float* c1buf;
  float* ctx; unsigned* bar;
};

// ---------------------------------------------------------------------------
// Persistent scan v2.1: 256 blocks x 512 threads (8 waves = 2/SIMD).
// __launch_bounds__(512, 2): LDS (100 KB) already limits to 1 block/CU =
// 2 waves/SIMD, so declare it -> 256-VGPR budget. Without it the compiler
// capped at 128 VGPR (r4 measured) and SPILLED the 160-VGPR weight arrays
// to scratch, re-loading them every step (the whole point of this kernel
// is zero per-step weight traffic).
// Wave = (wn col-half) x (kq K-quarter); weights in registers (w0 96 VGPR,
// w1 64 VGPR). Split-K partials via 4-plane gsm. lds0 carries h0 across the
// phase boundary -> only 2 coherent panel stages/step. Independent MFMA runs
// before each barrier wait.
// ---------------------------------------------------------------------------
__global__ __launch_bounds__(512, 2) void scan_kernel(ScanArgs A)
{
  __shared__ float gsm[4][32][68];
  __shared__ char lds0[32 * 1024];   // h0 panel (carried A<->B)
  __shared__ char lds1[32 * 1024];   // h1 panel
  const int tid = threadIdx.x;
  const int bid = blockIdx.x;
  const int ng = (bid & 7) + (((bid >> 3) & 3) << 3);
  const int mt = bid >> 5;
  const int m0 = mt * 32, n0 = ng * 64;
  const int lane = tid & 63, wid = tid >> 6;
  const int wn = wid & 1;            // col half (2 nt)
  const int kq = wid >> 1;           // K quarter
  const int kgrp = lane >> 4;
  const int r15 = lane & 15;
  const int r15b = r15 * 1024;
  const int r16b = (r15 + 16) * 1024;
  const int sw = (r15 & 7) << 4;
  const int arow0 = m0 + r15;
  const int erow = tid >> 4;         // epilogue: 0..31
  const int edl = tid & 15;
  const int d = ng * 16 + edl;
  const int eb = m0 + erow;
  unsigned* gbar = A.bar + mt * 512;

  // ---- one-time: weights into registers ----
  const int nt0 = ng * 4 + wn * 2;
  short8 w0[12][2], w1[8][2];
  {
    const short8* B0 = (const short8*)A.B0B;
    const short8* B1 = (const short8*)A.B1;
#pragma unroll
    for (int kc = 0; kc < 12; kc++) {
      w0[kc][0] = B0[((long)nt0 * 48 + kq * 12 + kc) * 64 + lane];
      w0[kc][1] = B0[((long)(nt0 + 1) * 48 + kq * 12 + kc) * 64 + lane];
    }
    const int kqB = kq ^ 2;   // kq0/1 hold h1p-range, kq2/3 hold h0n-range
#pragma unroll
    for (int kc = 0; kc < 8; kc++) {
      w1[kc][0] = B1[((long)nt0 * 32 + kqB * 8 + kc) * 64 + lane];
      w1[kc][1] = B1[((long)(nt0 + 1) * 32 + kqB * 8 + kc) * 64 + lane];
    }
  }
  const short8* bA0 = (const short8*)A.B0A + (long)nt0 * 36 * 64 + lane;
  const short8* bA1 = (const short8*)A.B0A + (long)(nt0 + 1) * 36 * 64 + lane;

  float biasAr[4], bias0r[4], bias1r[4];
#pragma unroll
  for (int g = 0; g < 4; g++) {
    biasAr[g] = A.bias0A[n0 + edl * 4 + g];
    bias0r[g] = A.bias0B[n0 + edl * 4 + g];
    bias1r[g] = A.bias1[n0 + edl * 4 + g];
  }
  float c0r = A.c0buf[eb * 512 + d];
  float c1r = A.c1buf[eb * 512 + d];

  short8 stg[4];
  short8 a0, a1;
  floatx4 acc00, acc01, acc10, acc11;

#define MFMA_ __builtin_amdgcn_mfma_f32_16x16x32_bf16
#define MF4(B0V, B1V) { acc00 = MFMA_(a0, (B0V), acc00, 0, 0, 0); \
                        acc01 = MFMA_(a0, (B1V), acc01, 0, 0, 0); \
                        acc10 = MFMA_(a1, (B0V), acc10, 0, 0, 0); \
                        acc11 = MFMA_(a1, (B1V), acc11, 0, 0, 0); }
#define XLD(c) { a0 = *(const short8*)(xt + (long)arow0 * 512 + (c) * 32 + kgrp * 8); \
                 a1 = *(const short8*)(xt + (long)(arow0 + 16) * 512 + (c) * 32 + kgrp * 8); }
#define LLD(P, cl) { int kb = (cl) * 64 + kgrp * 16; \
                     a0 = *(const short8*)((P) + r15b + (kb ^ sw)); \
                     a1 = *(const short8*)((P) + r16b + (kb ^ sw)); }
#define PLD(cl) { a0 = *(const short8*)(A.pred0pad + (long)arow0 * 128 + (cl) * 32 + kgrp * 8); \
                  a1 = *(const short8*)(A.pred0pad + (long)(arow0 + 16) * 128 + (cl) * 32 + kgrp * 8); }
#define ZACC { acc00 = (floatx4){0.f,0.f,0.f,0.f}; acc01 = acc00; acc10 = acc00; acc11 = acc00; }

  auto gsmw = [&]() {
#pragma unroll
    for (int r = 0; r < 4; r++) {
      gsm[kq][kgrp * 4 + r][wn * 32 + r15] = acc00[r];
      gsm[kq][kgrp * 4 + r][wn * 32 + 16 + r15] = acc01[r];
      gsm[kq][kgrp * 4 + r + 16][wn * 32 + r15] = acc10[r];
      gsm[kq][kgrp * 4 + r + 16][wn * 32 + 16 + r15] = acc11[r];
    }
  };

  for (int t = 0; t < 256; t++) {
    const int p = t & 1;
    const short* h0p = p ? A.h0b : A.h0a;
    short* h0n       = p ? A.h0a : A.h0b;
    const short* h1p = p ? A.h1b : A.h1a;
    short* h1n       = p ? A.h1a : A.h1b;
    const short* xt = A.xemb + (long)t * (256 * 512);

    // ================= phase A: LSTM0 =================
    ZACC;
    if (t == 0) {
      // streamed B0A (KC=36); stage h0p + h1p panels once
      stage_issue(stg, h0p, m0, tid);
      if (kq == 0) {
#pragma unroll
        for (int kc = 0; kc < 9; kc++) { XLD(kc); MF4(bA0[kc * 64], bA1[kc * 64]); }
      } else if (kq == 1) {
#pragma unroll
        for (int kc = 0; kc < 7; kc++) { XLD(9 + kc); MF4(bA0[(9 + kc) * 64], bA1[(9 + kc) * 64]); }
      }
      vmem_drain(); stage_write(lds0, stg, tid); __syncthreads();
      if (kq == 1) {
#pragma unroll
        for (int kc = 0; kc < 2; kc++) { LLD(lds0, kc); MF4(bA0[(16 + kc) * 64], bA1[(16 + kc) * 64]); }
      } else if (kq == 2) {
#pragma unroll
        for (int kc = 0; kc < 9; kc++) { LLD(lds0, 2 + kc); MF4(bA0[(18 + kc) * 64], bA1[(18 + kc) * 64]); }
      } else if (kq == 3) {
#pragma unroll
        for (int kc = 0; kc < 5; kc++) { LLD(lds0, 11 + kc); MF4(bA0[(27 + kc) * 64], bA1[(27 + kc) * 64]); }
      }
      stage_issue(stg, h1p, m0, tid);
      if (kq == 3) {
#pragma unroll
        for (int kc = 0; kc < 4; kc++) { PLD(kc); MF4(bA0[(32 + kc) * 64], bA1[(32 + kc) * 64]); }
      }
      vmem_drain(); stage_write(lds1, stg, tid); __syncthreads();
    } else {
      // independent work first: x (global) + h0 (carried in lds0 from phase B)
      if (kq == 0) {
#pragma unroll
        for (int kc = 0; kc < 12; kc++) { XLD(kc); MF4(w0[kc][0], w0[kc][1]); }
      } else if (kq == 1) {
#pragma unroll
        for (int kc = 0; kc < 4; kc++) { XLD(12 + kc); MF4(w0[kc][0], w0[kc][1]); }
#pragma unroll
        for (int kc = 4; kc < 12; kc++) { LLD(lds0, kc - 4); MF4(w0[kc][0], w0[kc][1]); }
      } else if (kq == 2) {
#pragma unroll
        for (int kc = 0; kc < 8; kc++) { LLD(lds0, 8 + kc); MF4(w0[kc][0], w0[kc][1]); }
      }
      bar_wait(gbar + 2 * t - 1);            // b_{t-1}: h1p ready
      stage_issue(stg, h1p, m0, tid);
      vmem_drain(); stage_write(lds1, stg, tid); __syncthreads();
      if (kq == 2) {
#pragma unroll
        for (int kc = 8; kc < 12; kc++) { LLD(lds1, kc - 8); MF4(w0[kc][0], w0[kc][1]); }
      } else if (kq == 3) {
#pragma unroll
        for (int kc = 0; kc < 12; kc++) { LLD(lds1, 4 + kc); MF4(w0[kc][0], w0[kc][1]); }
      }
    }
    gsmw();
    __syncthreads();
    {
      floatx4 s = *(const floatx4*)&gsm[0][erow][edl * 4];
#pragma unroll
      for (int pl = 1; pl < 4; pl++) {
        floatx4 q = *(const floatx4*)&gsm[pl][erow][edl * 4];
        s[0] += q[0]; s[1] += q[1]; s[2] += q[2]; s[3] += q[3];
      }
      const float* bA = t ? bias0r : biasAr;
      float gi = s[0] + bA[0], gf = s[1] + bA[1], gg = s[2] + bA[2], go = s[3] + bA[3];
      float is = 1.f / (1.f + __expf(-gi));
      float fs = 1.f / (1.f + __expf(-gf));
      float os = 1.f / (1.f + __expf(-go));
      float gt = tanhf(gg);
      float cn = fs * c0r + is * gt;
      c0r = cn;
      float hn = os * tanhf(cn);
      st2_coh(h0n + eb * 512 + d, (unsigned)(unsigned short)f2bf(hn));
    }
    bar_arrive(gbar + 2 * t);                // a_t

    // ================= phase B: LSTM1 =================
    ZACC;
    // independent: Whh1 x h1p from lds1 (kq0/1 hold that weight range)
    if (kq == 0) {
#pragma unroll
      for (int kc = 0; kc < 8; kc++) { LLD(lds1, kc); MF4(w1[kc][0], w1[kc][1]); }
    } else if (kq == 1) {
#pragma unroll
      for (int kc = 0; kc < 8; kc++) { LLD(lds1, 8 + kc); MF4(w1[kc][0], w1[kc][1]); }
    }
    bar_wait(gbar + 2 * t);                  // a_t: h0n ready
    stage_issue(stg, h0n, m0, tid);
    vmem_drain(); stage_write(lds0, stg, tid); __syncthreads();
    if (kq == 2) {
#pragma unroll
      for (int kc = 0; kc < 8; kc++) { LLD(lds0, kc); MF4(w1[kc][0], w1[kc][1]); }
    } else if (kq == 3) {
#pragma unroll
      for (int kc = 0; kc < 8; kc++) { LLD(lds0, 8 + kc); MF4(w1[kc][0], w1[kc][1]); }
    }
    gsmw();
    __syncthreads();
    {
      floatx4 s = *(const floatx4*)&gsm[0][erow][edl * 4];
#pragma unroll
      for (int pl = 1; pl < 4; pl++) {
        floatx4 q = *(const floatx4*)&gsm[pl][erow][edl * 4];
        s[0] += q[0]; s[1] += q[1]; s[2] += q[2]; s[3] += q[3];
      }
      float gi = s[0] + bias1r[0], gf = s[1] + bias1r[1];
      float gg = s[2] + bias1r[2], go = s[3] + bias1r[3];
      float is = 1.f / (1.f + __expf(-gi));
      float fs = 1.f / (1.f + __expf(-gf));
      float os = 1.f / (1.f + __expf(-go));
      float gt = tanhf(gg);
      float cn = fs * c1r + is * gt;
      c1r = cn;
      float hn = os * tanhf(cn);
      st2_coh(h1n + eb * 512 + d, (unsigned)(unsigned short)f2bf(hn));
      (A.ctx + (long)t * CTX)[(long)eb * (256L * CTX) + d] = hn;
    }
    if (t < 255) bar_arrive(gbar + 2 * t + 1);   // b_t
  }
}

extern "C" void kernel_launch(void* const* d_in, const int* in_sizes, int n_in,
                              void* d_out, int out_size, void* d_ws, size_t ws_size,
                              hipStream_t stream)
{
  const float* x       = (const float*)d_in[0];
  const float* init_p  = (const float*)d_in[1];
  const float* embed_W = (const float*)d_in[2];
  const float* embed_b = (const float*)d_in[3];
  const float* ni_W1   = (const float*)d_in[4];
  const float* ni_b1   = (const float*)d_in[5];
  const float* ni_W2   = (const float*)d_in[6];
  const float* ni_b2   = (const float*)d_in[7];
  const float* ni_W3   = (const float*)d_in[8];
  const float* ni_b3   = (const float*)d_in[9];
  const float* Wih0    = (const float*)d_in[10];
  const float* Whh0    = (const float*)d_in[11];
  const float* bih0    = (const float*)d_in[12];
  const float* bhh0    = (const float*)d_in[13];
  const float* Wih1    = (const float*)d_in[14];
  const float* Whh1    = (const float*)d_in[15];
  const float* bih1    = (const float*)d_in[16];
  const float* bhh1    = (const float*)d_in[17];
  const float* dec_W   = (const float*)d_in[18];
  const float* dec_b   = (const float*)d_in[19];
  float* out = (float*)d_out;
  char* ws = (char*)d_ws;

  // workspace layout (all 256B-aligned), ~86.1 MB
  short* xemb = (short*)(ws + 0);                 // [F][B][512] bf16, 67108864
  short* B0A  = (short*)(ws + 67108864);          // 36*32*2048*2 = 4718592
  short* B0B  = (short*)(ws + 71827456);          // 48*32*2048*2 = 6291456
  short* B1p  = (short*)(ws + 78118912);          // 32*32*2048*2 = 4194304
  short* Sh0[2] = { (short*)(ws + 82313216), (short*)(ws + 82575360) };
  short* Sh1[2] = { (short*)(ws + 82837504), (short*)(ws + 83099648) };
  float* c0     = (float*)(ws + 83361792);
  float* c1     = (float*)(ws + 83886080);
  float* bias0A = (float*)(ws + 84410368);
  float* bias0B = (float*)(ws + 84418560);
  float* bias1  = (float*)(ws + 84426752);
  short* pred0pad = (short*)(ws + 84434944);      // [256][128] bf16, 65536
  float* z1 = (float*)(ws + 84500480);
  float* z2 = (float*)(ws + 85024768);
  unsigned* bar = (unsigned*)(ws + 86073344);     // 8 groups x 512 counters
  (void)in_sizes; (void)n_in; (void)out_size; (void)ws_size;

  // ---- one-time prep (re-run every call; ws is re-poisoned by harness) ----
  pack_b<<<9216, 256, 0, stream>>>(B0A, 36, 0, Wih0, Whh0, Wih1, Whh1, dec_W);
  pack_b<<<12288, 256, 0, stream>>>(B0B, 48, 1, Wih0, Whh0, Wih1, Whh1, dec_W);
  pack_b<<<8192, 256, 0, stream>>>(B1p, 32, 2, Wih0, Whh0, Wih1, Whh1, dec_W);
  prep_small<<<128, 256, 0, stream>>>(bias0A, bias0B, bias1, pred0pad, bar,
                                      bih0, bhh0, bih1, bhh1, Wih0, dec_b, init_p);
  // x_emb = x @ embed_W + embed_b  -> bf16 [F][B][512]
  gemm_f32<<<dim3(8, 1024), 256, 0, stream>>>(x, 34, embed_W, embed_b,
      65536, 512, 34, 1, nullptr, nullptr, xemb, nullptr, nullptr, nullptr);
  // init MLP: z1 = relu(init@W1+b1); z2 = relu(z1@W2+b2); z3 = z2@W3+b3 -> h/c scatter
  gemm_f32<<<dim3(8, 4), 256, 0, stream>>>(init_p, 85, ni_W1, ni_b1,
      256, 512, 85, 0, z1, nullptr, nullptr, nullptr, nullptr, nullptr);
  gemm_f32<<<dim3(16, 4), 256, 0, stream>>>(z1, 512, ni_W2, ni_b2,
      256, 1024, 512, 0, z2, nullptr, nullptr, nullptr, nullptr, nullptr);
  gemm_f32<<<dim3(32, 4), 256, 0, stream>>>(z2, 1024, ni_W3, ni_b3,
      256, 2048, 1024, 2, nullptr, nullptr, Sh0[0], Sh1[0], c0, c1);

  // ---- persistent scan: ONE plain kernel, 256 blocks x 512 thr (1/CU) ----
  ScanArgs sa;
  sa.B0A = B0A; sa.B0B = B0B; sa.B1 = B1p;
  sa.bias0A = bias0A; sa.bias0B = bias0B; sa.bias1 = bias1;
  sa.xemb = xemb; sa.pred0pad = pred0pad;
  sa.h0a = Sh0[0]; sa.h0b = Sh0[1]; sa.h1a = Sh1[0]; sa.h1b = Sh1[1];
  sa.c0buf = c0; sa.c1buf = c1;
  sa.ctx = out + CTXOFF; sa.bar = bar;
  scan_kernel<<<256, 512, 0, stream>>>(sa);

  // ---- preds = ctx @ dec_W + dec_b -> pred_kp3d + motion_context[...,512:] ----
  gemm_f32<<<dim3(1, 1024), 256, 0, stream>>>(out + CTXOFF, CTX, dec_W, dec_b,
      65536, NJ3, 512, 3, out, out + CTXOFF, nullptr, nullptr, nullptr, nullptr);
}